// Round 16
// baseline (337.882 us; speedup 1.0000x reference)
//
#include <hip/hip_runtime.h>
#include <math.h>

#define PI_F 3.14159265358979323846f

typedef __attribute__((ext_vector_type(8))) short short8;
typedef __attribute__((ext_vector_type(4))) float f32x4;

__device__ __forceinline__ unsigned short f2bf(float f) {
    unsigned int u = __float_as_uint(f);
    unsigned int r = (u + 0x7fffu + ((u >> 16) & 1u)) >> 16;
    return (unsigned short)r;
}
__device__ __forceinline__ float bf2f(unsigned short v) {
    return __uint_as_float((unsigned int)v << 16);
}

// ---------------- prep_all: S4 prep (blocks 0..319) + w repack + bn-acc zero --------
__global__ __launch_bounds__(128) void prep_all(
    const float* __restrict__ ldt_a, const float* __restrict__ C2_a,
    const float* __restrict__ Dv_a,
    unsigned short* __restrict__ TA_a, unsigned short* __restrict__ VA_a,
    float* __restrict__ rs_a, float* __restrict__ Vrs_a,
    const float* __restrict__ ldt_b, const float* __restrict__ C2_b,
    const float* __restrict__ Dv_b,
    unsigned short* __restrict__ TA_b, unsigned short* __restrict__ VA_b,
    float* __restrict__ rs_b, float* __restrict__ Vrs_b,
    const float* __restrict__ w0, const float* __restrict__ w1,
    const float* __restrict__ w2, const float* __restrict__ w3,
    const float* __restrict__ w4, const float* __restrict__ w5,
    const float* __restrict__ w6, const float* __restrict__ w7,
    unsigned short* __restrict__ wprep, float* __restrict__ bnsum)
{
    int bid = blockIdx.x, t = threadIdx.x;
    if (bid >= 320) {
        int z = (bid - 320) * 128 + t;
        if (z < 20480) bnsum[z] = 0.f;          // bsum1[8][256][2] + bsum2[8][1024][2]
        const float* wsrc[8] = {w0, w1, w2, w3, w4, w5, w6, w7};
        int e0 = (bid - 320) * 256 + t;
#pragma unroll
        for (int half = 0; half < 2; half++) {
            int e = e0 + half * 128;
            if (e < 835584) {
                int id; int doff; int Cin;
                if (e < 49152) { id = e / 12288; doff = id * 12288; Cin = 64; }
                else { id = 4 + (e - 49152) / 196608; doff = 49152 + (id - 4) * 196608; Cin = 256; }
                int el = e - doff;
                int kb = el / (Cin * 32);
                int rem = el - kb * (Cin * 32);
                int o = rem >> 5, kk = rem & 31;
                int cch = kb / 6, t6 = kb % 6, k = t6 >> 1, chalf = t6 & 1;
                int c = cch * 64 + chalf * 32 + kk;
                wprep[e] = f2bf(wsrc[id][((size_t)o * Cin + c) * 3 + k]);
            }
        }
        return;
    }
    const float* log_dt; const float* C2; const float* Dv;
    unsigned short* TA; unsigned short* VA; float* rs; float* Vrs; int h;
    if (bid < 64) { h = bid;      log_dt = ldt_a; C2 = C2_a; Dv = Dv_a; TA = TA_a; VA = VA_a; rs = rs_a; Vrs = Vrs_a; }
    else          { h = bid - 64; log_dt = ldt_b; C2 = C2_b; Dv = Dv_b; TA = TA_b; VA = VA_b; rs = rs_b; Vrs = Vrs_b; }
    __shared__ float cn[64];
    __shared__ float sK[128];
    __shared__ unsigned short s_w[128 * 66];   // W staged [m][j], pad 66
    float dt = expf(log_dt[h]);
    if (t < 32) {
        int n = t;
        float e = expf(-0.5f*dt);
        float s_, c_; sincosf(PI_F*dt*n, &s_, &c_);
        float wr = e*c_, wi = e*s_;
        float ar = -0.5f, ai = PI_F*n;
        float den = 1.f/(ar*ar + ai*ai);
        float tr = wr - 1.f, ti = wi;
        float qr = (tr*ar + ti*ai)*den;
        float qi = (ti*ar - tr*ai)*den;
        float c2r = C2[((size_t)h*32+n)*2], c2i = C2[((size_t)h*32+n)*2+1];
        cn[2*n]   = 2.f*(c2r*qr - c2i*qi);
        cn[2*n+1] = 2.f*(c2r*qi + c2i*qr);
        float e128 = expf(-64.f*dt);
        float s2, c2v; sincosf(PI_F*dt*n*128.f, &s2, &c2v);
        float pr = 1.f - e128*c2v, pim = -e128*s2;
        float dr = 1.f - wr, di = -wi;
        float dd = 1.f/(dr*dr + di*di);
        Vrs[(size_t)h*64 + 2*n]   = (pr*dr + pim*di)*dd;
        Vrs[(size_t)h*64 + 2*n+1] = (pim*dr - pr*di)*dd;
    }
    __syncthreads();
    {
        float em = expf(-0.5f*dt*t);
        float Kt = 0.f;
        for (int n = 0; n < 32; n++) {
            float s_, c_; sincosf(PI_F*dt*(float)(n*t), &s_, &c_);
            Kt += cn[2*n]*em*c_ - cn[2*n+1]*em*s_;
        }
        sK[t] = Kt + (t == 0 ? Dv[h] : 0.f);
    }
    if (t < 64) {
        int n = t >> 1, ri = t & 1;
        float e = expf(-0.5f*dt);
        float s_, c_; sincosf(PI_F*dt*n, &s_, &c_);
        float wr = e*c_, wi = e*s_;
        float crn = cn[2*n], cin = cn[2*n+1];
        float pr = wr, pim = wi;                    // w^(m+1), m=0
        for (int m = 0; m < 128; m++) {
            float re = crn*pr - cin*pim;
            float im = crn*pim + cin*pr;
            s_w[m*66 + t] = f2bf(ri ? -im : re);
            float nr = pr*wr - pim*wi;
            float ni = pr*wi + pim*wr;
            pr = nr; pim = ni;
        }
    } else {
        int r = t - 64; int n = r >> 1, ri = r & 1;
        float e = expf(-0.5f*dt);
        float s_, c_; sincosf(PI_F*dt*n, &s_, &c_);
        float wr = e*c_, wi = e*s_;
        float cr2 = 1.f, ci2 = 0.f;                 // w^0
        for (int kb = 3; kb >= 0; kb--) {
            unsigned short buf[32];
            for (int kk = 31; kk >= 0; kk--) {
                buf[kk] = f2bf(ri ? ci2 : cr2);
                float nr = cr2*wr - ci2*wi;
                float ni = cr2*wi + ci2*wr;
                cr2 = nr; ci2 = ni;
            }
            uint4* dst = (uint4*)&VA[(((size_t)h*4 + kb)*64 + r)*32];
            uint4* src = (uint4*)buf;
            dst[0]=src[0]; dst[1]=src[1]; dst[2]=src[2]; dst[3]=src[3];
        }
    }
    __syncthreads();
    {
        float acc = 0.f;
        for (int tau = 0; tau <= t; tau++) acc += sK[tau];
        rs[(size_t)h*128 + t] = acc;
    }
    for (int kb = 0; kb < 4; kb++) {
        unsigned short tb[32];
#pragma unroll
        for (int kk = 0; kk < 32; kk++) {
            int col = kb*32 + kk;
            tb[kk] = f2bf((col <= t) ? sK[t - col] : 0.f);
        }
        uint4* dst = (uint4*)&TA[(((size_t)h*6 + kb)*128 + t)*32];
        uint4* src = (uint4*)tb;
        dst[0]=src[0]; dst[1]=src[1]; dst[2]=src[2]; dst[3]=src[3];
    }
    for (int i = t; i < 1024; i += 128) {
        int kb = i >> 9;
        int rem = i & 511;
        int m = rem >> 2, kkg = rem & 3;
        *(uint4*)&TA[(((size_t)h*6 + 4 + kb)*128 + m)*32 + kkg*8] =
            *(const uint4*)&s_w[m*66 + kb*32 + kkg*8];
    }
}

// ---------------- S4 layer fused: [enc] + [BN finalize] + V-GEMM + scan + T/W-GEMM --
template<int NCH, int LOGNCH, bool ENC, bool BN>
__global__ __launch_bounds__(256) void s4_layer_fused(
    const unsigned short* __restrict__ u, const float* __restrict__ xg,
    const float* __restrict__ ew, const float* __restrict__ ebv,
    const unsigned short* __restrict__ VA,
    const float* __restrict__ Vrs, const unsigned short* __restrict__ TA,
    const float* __restrict__ rs,
    const float* __restrict__ bnsum, const float* __restrict__ bng,
    const float* __restrict__ bnb, int bnC, int bnN, int gmask,
    const float* __restrict__ log_dt,
    unsigned short* __restrict__ yout)
{
    const int L = NCH * 128;
    __shared__ unsigned short s_u[64*200];   // 25600 B
    __shared__ unsigned short s_s[64*72];    // 9216 B
    __shared__ float sE[64*68];              // 17408 B  (total 52224 B)
    int h = blockIdx.y;
    int tid = threadIdx.x;
    int lane = tid & 63, wid = tid >> 6;
    int nl = lane & 15, g = lane >> 4;
    int col0 = blockIdx.x * 64;
    float scv = 1.f, shv = 0.f;
    if constexpr (BN) {
        float s1 = 0.f, s2 = 0.f;
#pragma unroll
        for (int k = 0; k < 8; k++) {
            s1 += bnsum[((size_t)k*bnC + h)*2];
            s2 += bnsum[((size_t)k*bnC + h)*2 + 1];
        }
        float m = s1 / (float)bnN;
        float var = s2 / (float)bnN - m*m;
        float rstd = rsqrtf(var + 1e-5f);
        scv = bng[h & gmask] * rstd;
        shv = fmaf(-m, scv, bnb[h & gmask]);
    }

    // stage u (once; serves V-GEMM and T-GEMM)
    if constexpr (ENC) {
        float w0e = ew[2*h], w1e = ew[2*h+1], bbe = ebv[h];
        for (int i = tid; i < 1024; i += 256) {
            int cl = i >> 4, o = i & 15;
            int col = col0 + cl; int b = col >> LOGNCH, c = col & (NCH - 1);
            const float* xp = xg + ((size_t)b*8192 + (size_t)(c*128 + o*8))*2;
            float4 a0 = *(const float4*)xp;
            float4 a1 = *(const float4*)(xp + 4);
            float4 a2 = *(const float4*)(xp + 8);
            float4 a3 = *(const float4*)(xp + 12);
            ushort4 q0, q1;
            q0.x = f2bf(fmaf(w0e, a0.x, fmaf(w1e, a0.y, bbe)));
            q0.y = f2bf(fmaf(w0e, a0.z, fmaf(w1e, a0.w, bbe)));
            q0.z = f2bf(fmaf(w0e, a1.x, fmaf(w1e, a1.y, bbe)));
            q0.w = f2bf(fmaf(w0e, a1.z, fmaf(w1e, a1.w, bbe)));
            q1.x = f2bf(fmaf(w0e, a2.x, fmaf(w1e, a2.y, bbe)));
            q1.y = f2bf(fmaf(w0e, a2.z, fmaf(w1e, a2.w, bbe)));
            q1.z = f2bf(fmaf(w0e, a3.x, fmaf(w1e, a3.y, bbe)));
            q1.w = f2bf(fmaf(w0e, a3.z, fmaf(w1e, a3.w, bbe)));
            *(ushort4*)&s_u[cl*200 + o*8]     = q0;
            *(ushort4*)&s_u[cl*200 + o*8 + 4] = q1;
        }
    } else {
        for (int i = tid; i < 1024; i += 256) {
            int cl = i >> 4, o = i & 15;
            int col = col0 + cl; int b = col >> LOGNCH, c = col & (NCH - 1);
            *(uint4*)&s_u[cl*200 + o*8] =
                *(const uint4*)&u[((size_t)h*16 + b)*L + c*128 + o*8];
        }
    }
    __syncthreads();

    // V-GEMM: wave wid computes E for cols cl = wid*16 + nl (gemm_a math)
    {
        int cl = wid*16 + nl;
        f32x4 acc[4];
#pragma unroll
        for (int mt = 0; mt < 4; mt++) acc[mt] = (f32x4){0.f,0.f,0.f,0.f};
#pragma unroll
        for (int kb = 0; kb < 4; kb++) {
            short8 bf = *(const short8*)&s_u[cl*200 + kb*32 + g*8];
#pragma unroll
            for (int mt = 0; mt < 4; mt++) {
                short8 af = *(const short8*)(VA + (((size_t)h*4 + kb)*64 + mt*16 + nl)*32 + g*8);
                acc[mt] = __builtin_amdgcn_mfma_f32_16x16x32_bf16(af, bf, acc[mt], 0, 0, 0);
            }
        }
#pragma unroll
        for (int mt = 0; mt < 4; mt++) {
            int j0 = mt*16 + g*4;
            float4 vr = *(const float4*)(Vrs + (size_t)h*64 + j0);
            sE[cl*68 + j0 + 0] = fmaf(scv, acc[mt][0], shv*vr.x);
            sE[cl*68 + j0 + 1] = fmaf(scv, acc[mt][1], shv*vr.y);
            sE[cl*68 + j0 + 2] = fmaf(scv, acc[mt][2], shv*vr.z);
            sE[cl*68 + j0 + 3] = fmaf(scv, acc[mt][3], shv*vr.w);
        }
    }
    __syncthreads();

    // chunk scan (mid math)
    constexpr int NB = 64 / NCH;   // 1 (layer a) or 4 (layer b)
    if (tid < NB * 32) {
        int bl = tid >> 5, n = tid & 31;
        float dt = expf(log_dt[h]);
        float e = expf(-0.5f * dt);
        float s_, c_; sincosf(PI_F * dt * n, &s_, &c_);
        float Wr = e*c_, Wi = e*s_;
#pragma unroll
        for (int i = 0; i < 7; i++) { float r = Wr*Wr - Wi*Wi; float im = 2.f*Wr*Wi; Wr = r; Wi = im; }
        float Sr = 0.f, Si = 0.f;
        for (int c2 = 0; c2 < NCH; c2++) {
            float* ep = &sE[(bl*NCH + c2)*68 + 2*n];
            float er = ep[0], ei = ep[1];
            ep[0] = Sr; ep[1] = Si;          // Sini = state BEFORE chunk c2
            float r  = fmaf(Wr, Sr, fmaf(-Wi, Si, er));
            float im = fmaf(Wi, Sr, fmaf( Wr, Si, ei));
            Sr = r; Si = im;
        }
    }
    __syncthreads();

    // convert Sini (fp32 in sE) -> bf16 s_s
    for (int i = tid*4; i < 4096; i += 1024) {
        int cl = i >> 6, j = i & 63;
        ushort4 q;
        q.x = f2bf(sE[cl*68 + j]);
        q.y = f2bf(sE[cl*68 + j+1]);
        q.z = f2bf(sE[cl*68 + j+2]);
        q.w = f2bf(sE[cl*68 + j+3]);
        *(ushort4*)&s_s[cl*72 + j] = q;
    }
    __syncthreads();

    // T-GEMM + W-GEMM + epilogue
    f32x4 accT[2][4], accW[2][4];
#pragma unroll
    for (int a = 0; a < 2; a++)
#pragma unroll
        for (int j = 0; j < 4; j++) { accT[a][j] = (f32x4){0,0,0,0}; accW[a][j] = (f32x4){0,0,0,0}; }
#pragma unroll
    for (int kb = 0; kb < 4; kb++) {
        short8 bfr[4];
#pragma unroll
        for (int j = 0; j < 4; j++)
            bfr[j] = *(const short8*)&s_u[(j*16 + nl)*200 + kb*32 + g*8];
#pragma unroll
        for (int mt2 = 0; mt2 < 2; mt2++) {
            int mtile = wid*2 + mt2;
            short8 af = *(const short8*)&TA[(((size_t)h*6 + kb)*128 + mtile*16 + nl)*32 + g*8];
#pragma unroll
            for (int j = 0; j < 4; j++)
                accT[mt2][j] = __builtin_amdgcn_mfma_f32_16x16x32_bf16(af, bfr[j], accT[mt2][j], 0, 0, 0);
        }
    }
#pragma unroll
    for (int kw = 0; kw < 2; kw++) {
        short8 bfr[4];
#pragma unroll
        for (int j = 0; j < 4; j++)
            bfr[j] = *(const short8*)&s_s[(j*16 + nl)*72 + kw*32 + g*8];
#pragma unroll
        for (int mt2 = 0; mt2 < 2; mt2++) {
            int mtile = wid*2 + mt2;
            short8 af = *(const short8*)&TA[(((size_t)h*6 + 4 + kw)*128 + mtile*16 + nl)*32 + g*8];
#pragma unroll
            for (int j = 0; j < 4; j++)
                accW[mt2][j] = __builtin_amdgcn_mfma_f32_16x16x32_bf16(af, bfr[j], accW[mt2][j], 0, 0, 0);
        }
    }
#pragma unroll
    for (int mt2 = 0; mt2 < 2; mt2++) {
        int m0 = (wid*2 + mt2)*16 + g*4;
        float4 rsv = *(const float4*)&rs[(size_t)h*128 + m0];
#pragma unroll
        for (int j = 0; j < 4; j++) {
            int col = col0 + j*16 + nl; int b = col >> LOGNCH, c = col & (NCH - 1);
            ushort4 q;
            q.x = f2bf(fmaf(scv, accT[mt2][j][0], shv*rsv.x) + accW[mt2][j][0]);
            q.y = f2bf(fmaf(scv, accT[mt2][j][1], shv*rsv.y) + accW[mt2][j][1]);
            q.z = f2bf(fmaf(scv, accT[mt2][j][2], shv*rsv.z) + accW[mt2][j][2]);
            q.w = f2bf(fmaf(scv, accT[mt2][j][3], shv*rsv.w) + accW[mt2][j][3]);
            *(ushort4*)&yout[((size_t)h*16 + b)*L + c*128 + m0] = q;
        }
    }
}

// ---------------- fused 4-dilation conv block via MFMA (v8 config + BN partials) ----
// Structure FROZEN at v8 config (spill-fragile; see rounds 2/5/14). Added: post-store
// BN partial sums from acc (transient regs only): per (m,r2) sum over f, shfl-reduce
// over the 16 nl lanes, lane nl==0 atomicAdds into bnacc bank (blockIdx.x & 7).
template<int CIN, int TBLK>
__global__ __launch_bounds__(256, 2) void conv_mfma4(
    const unsigned short* __restrict__ u, const unsigned short* __restrict__ wp,
    const float* __restrict__ bs0, const float* __restrict__ bs1,
    const float* __restrict__ bs2, const float* __restrict__ bs3,
    unsigned short* __restrict__ out, float* __restrict__ bnacc,
    int Lin, int Lout)
{
    constexpr int F     = TBLK / 16;
    constexpr int NPOS  = TBLK * 4 + 16;
    constexpr int Q     = NPOS / 4;
    constexpr int NITEM = (NPOS / 8) * 64;
    constexpr int NLD   = (NITEM + 255) / 256;
    constexpr int NCC   = CIN / 64;
    constexpr int NBUF  = (NCC > 1) ? 2 : 1;
    constexpr int BUFSZ = 4 * Q * 64;
    __shared__ unsigned short s_in[NBUF * BUFSZ];

    int tid = threadIdx.x;
    int lane = tid & 63, wid = tid >> 6;      // wid == dilation index d
    int nl = lane & 15, g = lane >> 4;
    int t0 = blockIdx.x * TBLK;
    int b  = blockIdx.y;
    int og = blockIdx.z * 64;
    const int P0 = t0 * 4 - 8;
    const int DIL = 1 << wid;                 // wave-uniform

    f32x4 acc[4][F];
#pragma unroll
    for (int m = 0; m < 4; m++)
#pragma unroll
        for (int f = 0; f < F; f++) acc[m][f] = (f32x4){0.f,0.f,0.f,0.f};

    uint4 stg[NLD];

    auto stage_load = [&](int ccbase) {
#pragma unroll
        for (int j = 0; j < NLD; j++) {
            int i = tid + 256 * j;
            uint4 v; v.x = 0u; v.y = 0u; v.z = 0u; v.w = 0u;
            if (i < NITEM) {
                int ch = i & 63, po = i >> 6;
                int p = P0 + po * 8;
                const unsigned short* gp = u + ((size_t)(ccbase + ch)*16 + b)*Lin;
                if (p >= 0 && p + 8 <= Lin) {
                    v = *(const uint4*)(gp + p);
                } else {
                    alignas(16) unsigned short t8[8];
#pragma unroll
                    for (int j2 = 0; j2 < 8; j2++) {
                        int pj = p + j2;
                        t8[j2] = ((unsigned)pj < (unsigned)Lin) ? gp[pj] : (unsigned short)0;
                    }
                    v = *(const uint4*)t8;
                }
            }
            stg[j] = v;
        }
    };
    auto stage_write = [&](int bufidx) {
        unsigned short* sb = s_in + bufidx * BUFSZ;
#pragma unroll
        for (int j = 0; j < NLD; j++) {
            int i = tid + 256 * j;
            if (i < NITEM) {
                int ch = i & 63, po = i >> 6;
                alignas(16) unsigned short t8[8];
                *(uint4*)t8 = stg[j];
#pragma unroll
                for (int jj = 0; jj < 8; jj++) {
                    int pl = po * 8 + jj;
                    int row = (pl & 3) * Q + (pl >> 2);
                    sb[row * 64 + (ch ^ ((row & 7) << 3))] = t8[jj];
                }
            }
        }
    };

    stage_load(0);
    stage_write(0);
    __syncthreads();

#pragma unroll
    for (int cc = 0; cc < NCC; cc++) {
        if (cc + 1 < NCC) stage_load((cc + 1) * 64);
        const unsigned short* sb = s_in + (NBUF > 1 ? (cc & 1) * BUFSZ : 0);
#pragma unroll
        for (int k = 0; k < 3; ++k) {
            const int off = (k - 1) * DIL + 8;
            const int r = off & 3, s = off >> 2;
#pragma unroll
            for (int chalf = 0; chalf < 2; ++chalf) {
                int kb = cc * 6 + k * 2 + chalf;
                short8 bfr[F];
#pragma unroll
                for (int f = 0; f < F; ++f) {
                    int q = f*16 + nl + s;
                    int row = r * Q + q;
                    bfr[f] = *(const short8*)&sb[row * 64 +
                        ((((chalf << 2) | g) ^ (row & 7)) << 3)];
                }
#pragma unroll
                for (int m = 0; m < 4; ++m) {
                    short8 afrag = *(const short8*)&wp[(size_t)wid*(3*CIN*CIN) +
                        ((size_t)kb*CIN + og + m*16 + nl)*32 + g*8];
#pragma unroll
                    for (int f = 0; f < F; ++f)
                        acc[m][f] = __builtin_amdgcn_mfma_f32_16x16x32_bf16(afrag, bfr[f], acc[m][f], 0, 0, 0);
                }
            }
        }
        if (cc + 1 < NCC) {
            __syncthreads();
            stage_write((cc + 1) & 1);
            __syncthreads();
        }
    }

    const float* bp = (wid == 0) ? bs0 : (wid == 1) ? bs1 : (wid == 2) ? bs2 : bs3;
#pragma unroll
    for (int m = 0; m < 4; ++m) {
#pragma unroll
        for (int f = 0; f < F; ++f) {
            int t = t0 + f*16 + nl;
#pragma unroll
            for (int r2 = 0; r2 < 4; ++r2) {
                int o = og + m*16 + g*4 + r2;
                float v = acc[m][f][r2] + bp[o];
                if (wid) v = v >= 0.f ? v : 0.3f*v;
                out[((size_t)(wid*CIN + o)*16 + b)*Lout + t] = f2bf(v);
            }
        }
    }

    // BN partial sums (recomputed from acc; transient registers only)
    float* bacc = bnacc + (size_t)(blockIdx.x & 7) * (4*CIN) * 2;
#pragma unroll
    for (int m = 0; m < 4; ++m) {
#pragma unroll
        for (int r2 = 0; r2 < 4; ++r2) {
            int o = og + m*16 + g*4 + r2;
            float bv = bp[o];
            float s = 0.f, ss = 0.f;
#pragma unroll
            for (int f = 0; f < F; ++f) {
                float v = acc[m][f][r2] + bv;
                if (wid) v = v >= 0.f ? v : 0.3f*v;
                s += v; ss += v*v;
            }
#pragma unroll
            for (int off2 = 1; off2 < 16; off2 <<= 1) {
                s  += __shfl_xor(s, off2);
                ss += __shfl_xor(ss, off2);
            }
            if (nl == 0) {
                int ch = wid*CIN + o;
                atomicAdd(&bacc[ch*2],     s);
                atomicAdd(&bacc[ch*2 + 1], ss);
            }
        }
    }
}

// ---------------- s4c fused v3 + inline BN finalize --------------
__global__ __launch_bounds__(256) void s4c_all(
    const unsigned short* __restrict__ u,
    const float* __restrict__ bnsum, const float* __restrict__ bng,
    const float* __restrict__ bnb,
    const float* __restrict__ log_dt, const float* __restrict__ C2,
    const float* __restrict__ Dv, float* __restrict__ x3last)
{
    __shared__ float sE[64 * 68];              // 17408 B
    __shared__ float red[16 * 33];             // 2112 B
    __shared__ unsigned short sVA[4 * 64 * 32];// 16384 B
    __shared__ alignas(16) float sVrs[64];     // 256 B
    int h = blockIdx.x;
    int tid = threadIdx.x;
    int lane = tid & 63, wid = tid >> 6;
    int nl = lane & 15, g = lane >> 4;
    float dt = expf(log_dt[h]);
    // BN finalize (bn2): C=1024, n=8192, gmask=255
    float scv, shv;
    {
        float s1 = 0.f, s2 = 0.f;
#pragma unroll
        for (int k = 0; k < 8; k++) {
            s1 += bnsum[((size_t)k*1024 + h)*2];
            s2 += bnsum[((size_t)k*1024 + h)*2 + 1];
        }
        float m = s1 / 8192.f;
        float var = s2 / 8192.f - m*m;
        float rstd = rsqrtf(var + 1e-5f);
        scv = bng[h & 255] * rstd;
        shv = fmaf(-m, scv, bnb[h & 255]);
    }

    // build V rows + Vrs: thread (t=lane, kb=wid) builds 32 cols (chunk-swizzled)
    {
        int t = lane, n = t >> 1, ri = t & 1;
        int kb = wid;
        float e = expf(-0.5f*dt);
        float s_, c_; sincosf(PI_F*dt*n, &s_, &c_);
        float wr = e*c_, wi = e*s_;
        int e0 = 96 - kb*32;                     // exponent at (kb, kk=31)
        float em0 = expf(-0.5f*dt*(float)e0);
        float s0, c0; sincosf(PI_F*dt*(float)n*(float)e0, &s0, &c0);
        float cr2 = em0*c0, ci2 = em0*s0;        // w^e0 (e0=0 -> 1,0)
        alignas(16) unsigned short buf[32];
        for (int kk = 31; kk >= 0; kk--) {
            buf[kk] = f2bf(ri ? ci2 : cr2);
            float nr = cr2*wr - ci2*wi;
            float ni = cr2*wi + ci2*wr;
            cr2 = nr; ci2 = ni;
        }
        int key = (t >> 1) & 3;
        uint4* dst = (uint4*)&sVA[(kb*64 + t)*32];
        uint4* src4 = (uint4*)buf;
#pragma unroll
        for (int cc = 0; cc < 4; cc++) dst[cc ^ key] = src4[cc];
        if (wid == 0 && ri == 0) {
            float e128 = expf(-64.f*dt);
            float s2, c2v; sincosf(PI_F*dt*n*128.f, &s2, &c2v);
            float pr = 1.f - e128*c2v, pim = -e128*s2;
            float dr = 1.f - wr, di = -wi;
            float dd = 1.f/(dr*dr + di*di);
            sVrs[2*n]   = (pr*dr + pim*di)*dd;
            sVrs[2*n+1] = (pim*dr - pr*di)*dd;
        }
    }
    __syncthreads();

    // phase 1: wave wid handles col-group cg=wid (16 cols); all 4 in parallel
    int rkey = (nl >> 1) & 3;
    {
        int col = wid*16 + nl;
        int b = col >> 2, c = col & 3;
        const unsigned short* up = u + ((size_t)h*16 + b)*512 + c*128;
        f32x4 acc[4];
#pragma unroll
        for (int mt = 0; mt < 4; mt++) acc[mt] = (f32x4){0.f,0.f,0.f,0.f};
#pragma unroll
        for (int kb = 0; kb < 4; kb++) {
            short8 bf = *(const short8*)(up + kb*32 + g*8);
#pragma unroll
            for (int mt = 0; mt < 4; mt++) {
                short8 af = *(const short8*)&sVA[(kb*64 + mt*16 + nl)*32 + ((g ^ rkey) << 3)];
                acc[mt] = __builtin_amdgcn_mfma_f32_16x16x32_bf16(af, bf, acc[mt], 0, 0, 0);
            }
        }
#pragma unroll
        for (int mt = 0; mt < 4; mt++) {
            int j0 = mt*16 + g*4;
            float4 vr = *(const float4*)&sVrs[j0];
            sE[col*68 + j0 + 0] = fmaf(scv, acc[mt][0], shv*vr.x);
            sE[col*68 + j0 + 1] = fmaf(scv, acc[mt][1], shv*vr.y);
            sE[col*68 + j0 + 2] = fmaf(scv, acc[mt][2], shv*vr.z);
            sE[col*68 + j0 + 3] = fmaf(scv, acc[mt][3], shv*vr.w);
        }
    }
    __syncthreads();

    // phase 2+3 partials on wave 0: lane = (n, bh); each handles 8 b's
    if (tid < 64) {
        int n = lane >> 1, bh = lane & 1;
        float e = expf(-0.5f * dt);
        float s_, c_; sincosf(PI_F * dt * n, &s_, &c_);
        float wr = e*c_, wi = e*s_;
        float ar = -0.5f, ai = PI_F * n;
        float den = 1.f / (ar*ar + ai*ai);
        float tr = wr - 1.f, ti = wi;
        float qr = (tr*ar + ti*ai) * den;
        float qi = (ti*ar - tr*ai) * den;
        float c2r = C2[((size_t)h*32 + n)*2], c2i = C2[((size_t)h*32 + n)*2 + 1];
        float crv = c2r*qr - c2i*qi, civ = c2r*qi + c2i*qr;
        float Wr = wr, Wi = wi;
#pragma unroll
        for (int i = 0; i < 7; i++) { float r = Wr*Wr - Wi*Wi; float im = 2.f*Wr*Wi; Wr = r; Wi = im; }
#pragma unroll
        for (int b2 = 0; b2 < 8; b2++) {
            int b = bh*8 + b2;
            float Sr = 0.f, Si = 0.f;
#pragma unroll
            for (int c = 0; c < 4; c++) {
                int col = b*4 + c;
                float er = sE[col*68 + 2*n], ei = sE[col*68 + 2*n + 1];
                float r  = fmaf(Wr, Sr, fmaf(-Wi, Si, er));
                float im = fmaf(Wi, Sr, fmaf( Wr, Si, ei));
                Sr = r; Si = im;
            }
            red[b*33 + n] = crv*Sr - civ*Si;
        }
    }
    __syncthreads();
    if (tid < 16) {
        int b = tid;
        float s = 0.f;
        for (int n2 = 0; n2 < 32; n2++) s += red[b*33 + n2];
        float uv = fmaf(scv, bf2f(u[((size_t)h*16 + b)*512 + 511]), shv);
        x3last[b*1024 + h] = 2.f*s + Dv[h]*uv;
    }
}

// ---------------- decoder head ----------------
__global__ __launch_bounds__(256) void dec_kernel(
    const float* __restrict__ x3last, const float* __restrict__ w1, const float* __restrict__ b1,
    const float* __restrict__ w2, const float* __restrict__ b2, float* __restrict__ out)
{
    __shared__ float xs[1024];
    int b = blockIdx.x, tid = threadIdx.x;
    for (int i = tid; i < 1024; i += 256) xs[i] = x3last[b*1024 + i];
    __syncthreads();
    float z = b1[tid];
    const float* wpt = w1 + (size_t)tid*1024;
    for (int i = 0; i < 1024; i += 4) {
        float4 wv = *(const float4*)(wpt + i);
        z = fmaf(wv.x, xs[i],   z);
        z = fmaf(wv.y, xs[i+1], z);
        z = fmaf(wv.z, xs[i+2], z);
        z = fmaf(wv.w, xs[i+3], z);
    }
    float v = w2[tid] * z;
    for (int o = 32; o > 0; o >>= 1) v += __shfl_down(v, o);
    __shared__ float ps[4];
    if ((tid & 63) == 0) ps[tid >> 6] = v;
    __syncthreads();
    if (tid == 0) out[b] = ps[0] + ps[1] + ps[2] + ps[3] + b2[0];
}

extern "C" void kernel_launch(void* const* d_in, const int* in_sizes, int n_in,
                              void* d_out, int out_size, void* d_ws, size_t ws_size,
                              hipStream_t stream)
{
    const float* x       = (const float*)d_in[0];
    const float* enc_w   = (const float*)d_in[1];
    const float* enc_b   = (const float*)d_in[2];
    const float* s4a_ldt = (const float*)d_in[3];
    const float* s4a_C   = (const float*)d_in[4];
    const float* s4a_D   = (const float*)d_in[5];
    const float* s4b_ldt = (const float*)d_in[6];
    const float* s4b_C   = (const float*)d_in[7];
    const float* s4b_D   = (const float*)d_in[8];
    const float* s4c_ldt = (const float*)d_in[9];
    const float* s4c_C   = (const float*)d_in[10];
    const float* s4c_D   = (const float*)d_in[11];
    const float* b1w[4] = {(const float*)d_in[12], (const float*)d_in[14], (const float*)d_in[16], (const float*)d_in[18]};
    const float* b1b[4] = {(const float*)d_in[13], (const float*)d_in[15], (const float*)d_in[17], (const float*)d_in[19]};
    const float* b2w[4] = {(const float*)d_in[20], (const float*)d_in[22], (const float*)d_in[24], (const float*)d_in[26]};
    const float* b2b[4] = {(const float*)d_in[21], (const float*)d_in[23], (const float*)d_in[25], (const float*)d_in[27]};
    const float* bn1_g  = (const float*)d_in[28];
    const float* bn1_b  = (const float*)d_in[29];
    const float* bn2_g  = (const float*)d_in[30];
    const float* bn2_b  = (const float*)d_in[31];
    const float* dec1_w = (const float*)d_in[32];
    const float* dec1_b = (const float*)d_in[33];
    const float* dec2_w = (const float*)d_in[34];
    const float* dec2_b = (const float*)d_in[35];
    float* out = (float*)d_out;

    char* ws = (char*)d_ws;
    unsigned short* u3    = (unsigned short*)(ws);              // 16.8 MB
    unsigned short* ya    = (unsigned short*)(ws + 16777216);   // 16.8 MB (also yb)
    unsigned short* yb    = ya;
    unsigned short* u2    = (unsigned short*)(ws + 33554432);   // 16.8 MB
    unsigned short* wprep = (unsigned short*)(ws + 88080384);   // 1.67 MB
    unsigned short* TA_a  = (unsigned short*)(ws + 89751552);   // 3.15 MB
    unsigned short* TA_b  = (unsigned short*)(ws + 92897280);   // 12.6 MB
    unsigned short* VA_a  = (unsigned short*)(ws + 105480192);  // 1.05 MB
    unsigned short* VA_b  = (unsigned short*)(ws + 106528768);  // 4.2 MB
    float*          rs_a  = (float*)(ws + 110723072);           // 32 KB
    float*          rs_b  = (float*)(ws + 110755840);           // 128 KB
    float*          Vrs_a = (float*)(ws + 110886912);           // 16 KB
    float*          Vrs_b = (float*)(ws + 110903296);           // 64 KB
    float*          smallp= (float*)(ws + 110968832);
    float* bsum1 = smallp;           // [8][256][2]  = 4096 floats
    float* bsum2 = smallp + 4096;    // [8][1024][2] = 16384 floats
    float* x3l   = smallp + 20480;   // 16384 floats

    // prep: s4 A-matrices + conv weight repack + bn accumulator zero (one launch)
    prep_all<<<3584, 128, 0, stream>>>(
        s4a_ldt, s4a_C, s4a_D, TA_a, VA_a, rs_a, Vrs_a,
        s4b_ldt, s4b_C, s4b_D, TA_b, VA_b, rs_b, Vrs_b,
        b1w[0], b1w[1], b1w[2], b1w[3], b2w[0], b2w[1], b2w[2], b2w[3],
        wprep, bsum1);

    // s4a: fused with inline encoder (no BN input)
    s4_layer_fused<64,6,true,false><<<dim3(16, 64), 256, 0, stream>>>(
        nullptr, x, enc_w, enc_b, VA_a, Vrs_a, TA_a, rs_a,
        nullptr, nullptr, nullptr, 0, 0, 0, s4a_ldt, ya);

    // conv block1 -> u2 + bsum1 partials
    conv_mfma4<64,32><<<dim3(64, 16, 1), 256, 0, stream>>>(
        ya, wprep, b1b[0], b1b[1], b1b[2], b1b[3], u2, bsum1, 8192, 2048);

    // s4b: inline BN finalize (bn1: C=256, n=32768, gmask=63)
    s4_layer_fused<16,4,false,true><<<dim3(4, 256), 256, 0, stream>>>(
        u2, nullptr, nullptr, nullptr, VA_b, Vrs_b, TA_b, rs_b,
        bsum1, bn1_g, bn1_b, 256, 32768, 63, s4b_ldt, yb);

    // conv block2 -> u3 + bsum2 partials
    conv_mfma4<256,64><<<dim3(8, 16, 4), 256, 0, stream>>>(
        yb, wprep + 49152, b2b[0], b2b[1], b2b[2], b2b[3], u3, bsum2, 2048, 512);

    // s4c fused (inline bn2 finalize)
    s4c_all<<<1024, 256, 0, stream>>>(u3, bsum2, bn2_g, bn2_b, s4c_ldt, s4c_C, s4c_D, x3l);

    // decoder head
    dec_kernel<<<16, 256, 0, stream>>>(x3l, dec1_w, dec1_b, dec2_w, dec2_b, out);
}

// Round 17
// 297.093 us; speedup vs baseline: 1.1373x; 1.1373x over previous
//
#include <hip/hip_runtime.h>
#include <math.h>

#define PI_F 3.14159265358979323846f

typedef __attribute__((ext_vector_type(8))) short short8;
typedef __attribute__((ext_vector_type(4))) float f32x4;

__device__ __forceinline__ unsigned short f2bf(float f) {
    unsigned int u = __float_as_uint(f);
    unsigned int r = (u + 0x7fffu + ((u >> 16) & 1u)) >> 16;
    return (unsigned short)r;
}
__device__ __forceinline__ float bf2f(unsigned short v) {
    return __uint_as_float((unsigned int)v << 16);
}

// ---------------- prep_all: S4 prep (blocks 0..319) + conv weight repack (320+) -----
__global__ __launch_bounds__(128) void prep_all(
    const float* __restrict__ ldt_a, const float* __restrict__ C2_a,
    const float* __restrict__ Dv_a,
    unsigned short* __restrict__ TA_a, unsigned short* __restrict__ VA_a,
    float* __restrict__ rs_a, float* __restrict__ Vrs_a,
    const float* __restrict__ ldt_b, const float* __restrict__ C2_b,
    const float* __restrict__ Dv_b,
    unsigned short* __restrict__ TA_b, unsigned short* __restrict__ VA_b,
    float* __restrict__ rs_b, float* __restrict__ Vrs_b,
    const float* __restrict__ w0, const float* __restrict__ w1,
    const float* __restrict__ w2, const float* __restrict__ w3,
    const float* __restrict__ w4, const float* __restrict__ w5,
    const float* __restrict__ w6, const float* __restrict__ w7,
    unsigned short* __restrict__ wprep)
{
    int bid = blockIdx.x, t = threadIdx.x;
    if (bid >= 320) {
        const float* wsrc[8] = {w0, w1, w2, w3, w4, w5, w6, w7};
        int e0 = (bid - 320) * 256 + t;
#pragma unroll
        for (int half = 0; half < 2; half++) {
            int e = e0 + half * 128;
            if (e < 835584) {
                int id; int doff; int Cin;
                if (e < 49152) { id = e / 12288; doff = id * 12288; Cin = 64; }
                else { id = 4 + (e - 49152) / 196608; doff = 49152 + (id - 4) * 196608; Cin = 256; }
                int el = e - doff;
                int kb = el / (Cin * 32);
                int rem = el - kb * (Cin * 32);
                int o = rem >> 5, kk = rem & 31;
                int cch = kb / 6, t6 = kb % 6, k = t6 >> 1, chalf = t6 & 1;
                int c = cch * 64 + chalf * 32 + kk;
                wprep[e] = f2bf(wsrc[id][((size_t)o * Cin + c) * 3 + k]);
            }
        }
        return;
    }
    const float* log_dt; const float* C2; const float* Dv;
    unsigned short* TA; unsigned short* VA; float* rs; float* Vrs; int h;
    if (bid < 64) { h = bid;      log_dt = ldt_a; C2 = C2_a; Dv = Dv_a; TA = TA_a; VA = VA_a; rs = rs_a; Vrs = Vrs_a; }
    else          { h = bid - 64; log_dt = ldt_b; C2 = C2_b; Dv = Dv_b; TA = TA_b; VA = VA_b; rs = rs_b; Vrs = Vrs_b; }
    __shared__ float cn[64];
    __shared__ float sK[128];
    __shared__ unsigned short s_w[128 * 66];   // W staged [m][j], pad 66
    float dt = expf(log_dt[h]);
    if (t < 32) {
        int n = t;
        float e = expf(-0.5f*dt);
        float s_, c_; sincosf(PI_F*dt*n, &s_, &c_);
        float wr = e*c_, wi = e*s_;
        float ar = -0.5f, ai = PI_F*n;
        float den = 1.f/(ar*ar + ai*ai);
        float tr = wr - 1.f, ti = wi;
        float qr = (tr*ar + ti*ai)*den;
        float qi = (ti*ar - tr*ai)*den;
        float c2r = C2[((size_t)h*32+n)*2], c2i = C2[((size_t)h*32+n)*2+1];
        cn[2*n]   = 2.f*(c2r*qr - c2i*qi);
        cn[2*n+1] = 2.f*(c2r*qi + c2i*qr);
        float e128 = expf(-64.f*dt);
        float s2, c2v; sincosf(PI_F*dt*n*128.f, &s2, &c2v);
        float pr = 1.f - e128*c2v, pim = -e128*s2;
        float dr = 1.f - wr, di = -wi;
        float dd = 1.f/(dr*dr + di*di);
        Vrs[(size_t)h*64 + 2*n]   = (pr*dr + pim*di)*dd;
        Vrs[(size_t)h*64 + 2*n+1] = (pim*dr - pr*di)*dd;
    }
    __syncthreads();
    {
        float em = expf(-0.5f*dt*t);
        float Kt = 0.f;
        for (int n = 0; n < 32; n++) {
            float s_, c_; sincosf(PI_F*dt*(float)(n*t), &s_, &c_);
            Kt += cn[2*n]*em*c_ - cn[2*n+1]*em*s_;
        }
        sK[t] = Kt + (t == 0 ? Dv[h] : 0.f);
    }
    if (t < 64) {
        int n = t >> 1, ri = t & 1;
        float e = expf(-0.5f*dt);
        float s_, c_; sincosf(PI_F*dt*n, &s_, &c_);
        float wr = e*c_, wi = e*s_;
        float crn = cn[2*n], cin = cn[2*n+1];
        float pr = wr, pim = wi;                    // w^(m+1), m=0
        for (int m = 0; m < 128; m++) {
            float re = crn*pr - cin*pim;
            float im = crn*pim + cin*pr;
            s_w[m*66 + t] = f2bf(ri ? -im : re);
            float nr = pr*wr - pim*wi;
            float ni = pr*wi + pim*wr;
            pr = nr; pim = ni;
        }
    } else {
        int r = t - 64; int n = r >> 1, ri = r & 1;
        float e = expf(-0.5f*dt);
        float s_, c_; sincosf(PI_F*dt*n, &s_, &c_);
        float wr = e*c_, wi = e*s_;
        float cr2 = 1.f, ci2 = 0.f;                 // w^0
        for (int kb = 3; kb >= 0; kb--) {
            unsigned short buf[32];
            for (int kk = 31; kk >= 0; kk--) {
                buf[kk] = f2bf(ri ? ci2 : cr2);
                float nr = cr2*wr - ci2*wi;
                float ni = cr2*wi + ci2*wr;
                cr2 = nr; ci2 = ni;
            }
            uint4* dst = (uint4*)&VA[(((size_t)h*4 + kb)*64 + r)*32];
            uint4* src = (uint4*)buf;
            dst[0]=src[0]; dst[1]=src[1]; dst[2]=src[2]; dst[3]=src[3];
        }
    }
    __syncthreads();
    {
        float acc = 0.f;
        for (int tau = 0; tau <= t; tau++) acc += sK[tau];
        rs[(size_t)h*128 + t] = acc;
    }
    for (int kb = 0; kb < 4; kb++) {
        unsigned short tb[32];
#pragma unroll
        for (int kk = 0; kk < 32; kk++) {
            int col = kb*32 + kk;
            tb[kk] = f2bf((col <= t) ? sK[t - col] : 0.f);
        }
        uint4* dst = (uint4*)&TA[(((size_t)h*6 + kb)*128 + t)*32];
        uint4* src = (uint4*)tb;
        dst[0]=src[0]; dst[1]=src[1]; dst[2]=src[2]; dst[3]=src[3];
    }
    for (int i = t; i < 1024; i += 128) {
        int kb = i >> 9;
        int rem = i & 511;
        int m = rem >> 2, kkg = rem & 3;
        *(uint4*)&TA[(((size_t)h*6 + 4 + kb)*128 + m)*32 + kkg*8] =
            *(const uint4*)&s_w[m*66 + kb*32 + kkg*8];
    }
}

// ---------------- S4 layer fused: [enc] + V-GEMM + scan + T/W-GEMM ------------------
template<int NCH, int LOGNCH, bool ENC>
__global__ __launch_bounds__(256) void s4_layer_fused(
    const unsigned short* __restrict__ u, const float* __restrict__ xg,
    const float* __restrict__ ew, const float* __restrict__ ebv,
    const unsigned short* __restrict__ VA,
    const float* __restrict__ Vrs, const unsigned short* __restrict__ TA,
    const float* __restrict__ rs, const float* __restrict__ sc,
    const float* __restrict__ sh, const float* __restrict__ log_dt,
    unsigned short* __restrict__ yout)
{
    const int L = NCH * 128;
    __shared__ unsigned short s_u[64*200];   // 25600 B
    __shared__ unsigned short s_s[64*72];    // 9216 B
    __shared__ float sE[64*68];              // 17408 B  (total 52224 B)
    int h = blockIdx.y;
    int tid = threadIdx.x;
    int lane = tid & 63, wid = tid >> 6;
    int nl = lane & 15, g = lane >> 4;
    int col0 = blockIdx.x * 64;
    float scv = sc ? sc[h] : 1.f;
    float shv = sh ? sh[h] : 0.f;

    // stage u (once; serves V-GEMM and T-GEMM)
    if constexpr (ENC) {
        float w0e = ew[2*h], w1e = ew[2*h+1], bbe = ebv[h];
        for (int i = tid; i < 1024; i += 256) {
            int cl = i >> 4, o = i & 15;
            int col = col0 + cl; int b = col >> LOGNCH, c = col & (NCH - 1);
            const float* xp = xg + ((size_t)b*8192 + (size_t)(c*128 + o*8))*2;
            float4 a0 = *(const float4*)xp;
            float4 a1 = *(const float4*)(xp + 4);
            float4 a2 = *(const float4*)(xp + 8);
            float4 a3 = *(const float4*)(xp + 12);
            ushort4 q0, q1;
            q0.x = f2bf(fmaf(w0e, a0.x, fmaf(w1e, a0.y, bbe)));
            q0.y = f2bf(fmaf(w0e, a0.z, fmaf(w1e, a0.w, bbe)));
            q0.z = f2bf(fmaf(w0e, a1.x, fmaf(w1e, a1.y, bbe)));
            q0.w = f2bf(fmaf(w0e, a1.z, fmaf(w1e, a1.w, bbe)));
            q1.x = f2bf(fmaf(w0e, a2.x, fmaf(w1e, a2.y, bbe)));
            q1.y = f2bf(fmaf(w0e, a2.z, fmaf(w1e, a2.w, bbe)));
            q1.z = f2bf(fmaf(w0e, a3.x, fmaf(w1e, a3.y, bbe)));
            q1.w = f2bf(fmaf(w0e, a3.z, fmaf(w1e, a3.w, bbe)));
            *(ushort4*)&s_u[cl*200 + o*8]     = q0;
            *(ushort4*)&s_u[cl*200 + o*8 + 4] = q1;
        }
    } else {
        for (int i = tid; i < 1024; i += 256) {
            int cl = i >> 4, o = i & 15;
            int col = col0 + cl; int b = col >> LOGNCH, c = col & (NCH - 1);
            *(uint4*)&s_u[cl*200 + o*8] =
                *(const uint4*)&u[((size_t)h*16 + b)*L + c*128 + o*8];
        }
    }
    __syncthreads();

    // V-GEMM: wave wid computes E for cols cl = wid*16 + nl (gemm_a math)
    {
        int cl = wid*16 + nl;
        f32x4 acc[4];
#pragma unroll
        for (int mt = 0; mt < 4; mt++) acc[mt] = (f32x4){0.f,0.f,0.f,0.f};
#pragma unroll
        for (int kb = 0; kb < 4; kb++) {
            short8 bf = *(const short8*)&s_u[cl*200 + kb*32 + g*8];
#pragma unroll
            for (int mt = 0; mt < 4; mt++) {
                short8 af = *(const short8*)(VA + (((size_t)h*4 + kb)*64 + mt*16 + nl)*32 + g*8);
                acc[mt] = __builtin_amdgcn_mfma_f32_16x16x32_bf16(af, bf, acc[mt], 0, 0, 0);
            }
        }
#pragma unroll
        for (int mt = 0; mt < 4; mt++) {
            int j0 = mt*16 + g*4;
            float4 vr = *(const float4*)(Vrs + (size_t)h*64 + j0);
            sE[cl*68 + j0 + 0] = fmaf(scv, acc[mt][0], shv*vr.x);
            sE[cl*68 + j0 + 1] = fmaf(scv, acc[mt][1], shv*vr.y);
            sE[cl*68 + j0 + 2] = fmaf(scv, acc[mt][2], shv*vr.z);
            sE[cl*68 + j0 + 3] = fmaf(scv, acc[mt][3], shv*vr.w);
        }
    }
    __syncthreads();

    // chunk scan (mid math)
    constexpr int NB = 64 / NCH;   // 1 (layer a) or 4 (layer b)
    if (tid < NB * 32) {
        int bl = tid >> 5, n = tid & 31;
        float dt = expf(log_dt[h]);
        float e = expf(-0.5f * dt);
        float s_, c_; sincosf(PI_F * dt * n, &s_, &c_);
        float Wr = e*c_, Wi = e*s_;
#pragma unroll
        for (int i = 0; i < 7; i++) { float r = Wr*Wr - Wi*Wi; float im = 2.f*Wr*Wi; Wr = r; Wi = im; }
        float Sr = 0.f, Si = 0.f;
        for (int c2 = 0; c2 < NCH; c2++) {
            float* ep = &sE[(bl*NCH + c2)*68 + 2*n];
            float er = ep[0], ei = ep[1];
            ep[0] = Sr; ep[1] = Si;          // Sini = state BEFORE chunk c2
            float r  = fmaf(Wr, Sr, fmaf(-Wi, Si, er));
            float im = fmaf(Wi, Sr, fmaf( Wr, Si, ei));
            Sr = r; Si = im;
        }
    }
    __syncthreads();

    // convert Sini (fp32 in sE) -> bf16 s_s
    for (int i = tid*4; i < 4096; i += 1024) {
        int cl = i >> 6, j = i & 63;
        ushort4 q;
        q.x = f2bf(sE[cl*68 + j]);
        q.y = f2bf(sE[cl*68 + j+1]);
        q.z = f2bf(sE[cl*68 + j+2]);
        q.w = f2bf(sE[cl*68 + j+3]);
        *(ushort4*)&s_s[cl*72 + j] = q;
    }
    __syncthreads();

    // T-GEMM + W-GEMM + epilogue
    f32x4 accT[2][4], accW[2][4];
#pragma unroll
    for (int a = 0; a < 2; a++)
#pragma unroll
        for (int j = 0; j < 4; j++) { accT[a][j] = (f32x4){0,0,0,0}; accW[a][j] = (f32x4){0,0,0,0}; }
#pragma unroll
    for (int kb = 0; kb < 4; kb++) {
        short8 bfr[4];
#pragma unroll
        for (int j = 0; j < 4; j++)
            bfr[j] = *(const short8*)&s_u[(j*16 + nl)*200 + kb*32 + g*8];
#pragma unroll
        for (int mt2 = 0; mt2 < 2; mt2++) {
            int mtile = wid*2 + mt2;
            short8 af = *(const short8*)&TA[(((size_t)h*6 + kb)*128 + mtile*16 + nl)*32 + g*8];
#pragma unroll
            for (int j = 0; j < 4; j++)
                accT[mt2][j] = __builtin_amdgcn_mfma_f32_16x16x32_bf16(af, bfr[j], accT[mt2][j], 0, 0, 0);
        }
    }
#pragma unroll
    for (int kw = 0; kw < 2; kw++) {
        short8 bfr[4];
#pragma unroll
        for (int j = 0; j < 4; j++)
            bfr[j] = *(const short8*)&s_s[(j*16 + nl)*72 + kw*32 + g*8];
#pragma unroll
        for (int mt2 = 0; mt2 < 2; mt2++) {
            int mtile = wid*2 + mt2;
            short8 af = *(const short8*)&TA[(((size_t)h*6 + 4 + kw)*128 + mtile*16 + nl)*32 + g*8];
#pragma unroll
            for (int j = 0; j < 4; j++)
                accW[mt2][j] = __builtin_amdgcn_mfma_f32_16x16x32_bf16(af, bfr[j], accW[mt2][j], 0, 0, 0);
        }
    }
#pragma unroll
    for (int mt2 = 0; mt2 < 2; mt2++) {
        int m0 = (wid*2 + mt2)*16 + g*4;
        float4 rsv = *(const float4*)&rs[(size_t)h*128 + m0];
#pragma unroll
        for (int j = 0; j < 4; j++) {
            int col = col0 + j*16 + nl; int b = col >> LOGNCH, c = col & (NCH - 1);
            ushort4 q;
            q.x = f2bf(fmaf(scv, accT[mt2][j][0], shv*rsv.x) + accW[mt2][j][0]);
            q.y = f2bf(fmaf(scv, accT[mt2][j][1], shv*rsv.y) + accW[mt2][j][1]);
            q.z = f2bf(fmaf(scv, accT[mt2][j][2], shv*rsv.z) + accW[mt2][j][2]);
            q.w = f2bf(fmaf(scv, accT[mt2][j][3], shv*rsv.w) + accW[mt2][j][3]);
            *(ushort4*)&yout[((size_t)h*16 + b)*L + c*128 + m0] = q;
        }
    }
}

// ---------------- fused 4-dilation conv block via MFMA (v8 config, FROZEN) ----------
// Spill-fragile (rounds 2/5/14/16). ONLY clean config: LDS double-buffer, T14
// load-early/write-late, wave<->dilation remap, conv1 TBLK=32, conv2 TBLK=64,
// bounds (256,2), NO epilogue additions.
template<int CIN, int TBLK>
__global__ __launch_bounds__(256, 2) void conv_mfma4(
    const unsigned short* __restrict__ u, const unsigned short* __restrict__ wp,
    const float* __restrict__ bs0, const float* __restrict__ bs1,
    const float* __restrict__ bs2, const float* __restrict__ bs3,
    unsigned short* __restrict__ out, int Lin, int Lout)
{
    constexpr int F     = TBLK / 16;
    constexpr int NPOS  = TBLK * 4 + 16;
    constexpr int Q     = NPOS / 4;
    constexpr int NITEM = (NPOS / 8) * 64;
    constexpr int NLD   = (NITEM + 255) / 256;
    constexpr int NCC   = CIN / 64;
    constexpr int NBUF  = (NCC > 1) ? 2 : 1;
    constexpr int BUFSZ = 4 * Q * 64;
    __shared__ unsigned short s_in[NBUF * BUFSZ];

    int tid = threadIdx.x;
    int lane = tid & 63, wid = tid >> 6;      // wid == dilation index d
    int nl = lane & 15, g = lane >> 4;
    int t0 = blockIdx.x * TBLK;
    int b  = blockIdx.y;
    int og = blockIdx.z * 64;
    const int P0 = t0 * 4 - 8;
    const int DIL = 1 << wid;                 // wave-uniform

    f32x4 acc[4][F];
#pragma unroll
    for (int m = 0; m < 4; m++)
#pragma unroll
        for (int f = 0; f < F; f++) acc[m][f] = (f32x4){0.f,0.f,0.f,0.f};

    uint4 stg[NLD];

    auto stage_load = [&](int ccbase) {
#pragma unroll
        for (int j = 0; j < NLD; j++) {
            int i = tid + 256 * j;
            uint4 v; v.x = 0u; v.y = 0u; v.z = 0u; v.w = 0u;
            if (i < NITEM) {
                int ch = i & 63, po = i >> 6;
                int p = P0 + po * 8;
                const unsigned short* gp = u + ((size_t)(ccbase + ch)*16 + b)*Lin;
                if (p >= 0 && p + 8 <= Lin) {
                    v = *(const uint4*)(gp + p);
                } else {
                    alignas(16) unsigned short t8[8];
#pragma unroll
                    for (int j2 = 0; j2 < 8; j2++) {
                        int pj = p + j2;
                        t8[j2] = ((unsigned)pj < (unsigned)Lin) ? gp[pj] : (unsigned short)0;
                    }
                    v = *(const uint4*)t8;
                }
            }
            stg[j] = v;
        }
    };
    auto stage_write = [&](int bufidx) {
        unsigned short* sb = s_in + bufidx * BUFSZ;
#pragma unroll
        for (int j = 0; j < NLD; j++) {
            int i = tid + 256 * j;
            if (i < NITEM) {
                int ch = i & 63, po = i >> 6;
                alignas(16) unsigned short t8[8];
                *(uint4*)t8 = stg[j];
#pragma unroll
                for (int jj = 0; jj < 8; jj++) {
                    int pl = po * 8 + jj;
                    int row = (pl & 3) * Q + (pl >> 2);
                    sb[row * 64 + (ch ^ ((row & 7) << 3))] = t8[jj];
                }
            }
        }
    };

    stage_load(0);
    stage_write(0);
    __syncthreads();

#pragma unroll
    for (int cc = 0; cc < NCC; cc++) {
        if (cc + 1 < NCC) stage_load((cc + 1) * 64);
        const unsigned short* sb = s_in + (NBUF > 1 ? (cc & 1) * BUFSZ : 0);
#pragma unroll
        for (int k = 0; k < 3; ++k) {
            const int off = (k - 1) * DIL + 8;
            const int r = off & 3, s = off >> 2;
#pragma unroll
            for (int chalf = 0; chalf < 2; ++chalf) {
                int kb = cc * 6 + k * 2 + chalf;
                short8 bfr[F];
#pragma unroll
                for (int f = 0; f < F; ++f) {
                    int q = f*16 + nl + s;
                    int row = r * Q + q;
                    bfr[f] = *(const short8*)&sb[row * 64 +
                        ((((chalf << 2) | g) ^ (row & 7)) << 3)];
                }
#pragma unroll
                for (int m = 0; m < 4; ++m) {
                    short8 afrag = *(const short8*)&wp[(size_t)wid*(3*CIN*CIN) +
                        ((size_t)kb*CIN + og + m*16 + nl)*32 + g*8];
#pragma unroll
                    for (int f = 0; f < F; ++f)
                        acc[m][f] = __builtin_amdgcn_mfma_f32_16x16x32_bf16(afrag, bfr[f], acc[m][f], 0, 0, 0);
                }
            }
        }
        if (cc + 1 < NCC) {
            __syncthreads();
            stage_write((cc + 1) & 1);
            __syncthreads();
        }
    }

    const float* bp = (wid == 0) ? bs0 : (wid == 1) ? bs1 : (wid == 2) ? bs2 : bs3;
#pragma unroll
    for (int m = 0; m < 4; ++m) {
#pragma unroll
        for (int f = 0; f < F; ++f) {
            int t = t0 + f*16 + nl;
#pragma unroll
            for (int r2 = 0; r2 < 4; ++r2) {
                int o = og + m*16 + g*4 + r2;
                float v = acc[m][f][r2] + bp[o];
                if (wid) v = v >= 0.f ? v : 0.3f*v;
                out[((size_t)(wid*CIN + o)*16 + b)*Lout + t] = f2bf(v);
            }
        }
    }
}

// ---------------- BN stats from bf16 [ch][b][t] ----------------
__global__ __launch_bounds__(256) void bn_stats(
    const unsigned short* __restrict__ x, const float* __restrict__ g,
    const float* __restrict__ bb, float* __restrict__ sc, float* __restrict__ sh,
    int n, int gmask)
{
    int ch = blockIdx.x;
    const unsigned short* xp = x + (size_t)ch * n;
    float s1 = 0.f, s2 = 0.f;
    for (int i = threadIdx.x*8; i < n; i += 2048) {
        uint4 raw = *(const uint4*)(xp + i);
        unsigned short us[8]; *(uint4*)us = raw;
#pragma unroll
        for (int j = 0; j < 8; j++) {
            float v = bf2f(us[j]);
            s1 += v; s2 += v*v;
        }
    }
    for (int o = 32; o > 0; o >>= 1) { s1 += __shfl_down(s1, o); s2 += __shfl_down(s2, o); }
    __shared__ float p1[4], p2[4];
    int wid = threadIdx.x >> 6;
    if ((threadIdx.x & 63) == 0) { p1[wid] = s1; p2[wid] = s2; }
    __syncthreads();
    if (threadIdx.x == 0) {
        s1 = p1[0] + p1[1] + p1[2] + p1[3];
        s2 = p2[0] + p2[1] + p2[2] + p2[3];
        float m = s1 / n;
        float var = s2 / n - m*m;
        float rstd = rsqrtf(var + 1e-5f);
        float scale = g[ch & gmask] * rstd;
        sc[ch] = scale;
        sh[ch] = fmaf(-m, scale, bb[ch & gmask]);
    }
}

// ---------------- s4c fused v3 --------------
__global__ __launch_bounds__(256) void s4c_all(
    const unsigned short* __restrict__ u,
    const float* __restrict__ sc, const float* __restrict__ sh,
    const float* __restrict__ log_dt, const float* __restrict__ C2,
    const float* __restrict__ Dv, float* __restrict__ x3last)
{
    __shared__ float sE[64 * 68];              // 17408 B
    __shared__ float red[16 * 33];             // 2112 B
    __shared__ unsigned short sVA[4 * 64 * 32];// 16384 B
    __shared__ alignas(16) float sVrs[64];     // 256 B
    int h = blockIdx.x;
    int tid = threadIdx.x;
    int lane = tid & 63, wid = tid >> 6;
    int nl = lane & 15, g = lane >> 4;
    float scv = sc[h], shv = sh[h];
    float dt = expf(log_dt[h]);

    // build V rows + Vrs: thread (t=lane, kb=wid) builds 32 cols (chunk-swizzled)
    {
        int t = lane, n = t >> 1, ri = t & 1;
        int kb = wid;
        float e = expf(-0.5f*dt);
        float s_, c_; sincosf(PI_F*dt*n, &s_, &c_);
        float wr = e*c_, wi = e*s_;
        int e0 = 96 - kb*32;                     // exponent at (kb, kk=31)
        float em0 = expf(-0.5f*dt*(float)e0);
        float s0, c0; sincosf(PI_F*dt*(float)n*(float)e0, &s0, &c0);
        float cr2 = em0*c0, ci2 = em0*s0;        // w^e0 (e0=0 -> 1,0)
        alignas(16) unsigned short buf[32];
        for (int kk = 31; kk >= 0; kk--) {
            buf[kk] = f2bf(ri ? ci2 : cr2);
            float nr = cr2*wr - ci2*wi;
            float ni = cr2*wi + ci2*wr;
            cr2 = nr; ci2 = ni;
        }
        int key = (t >> 1) & 3;
        uint4* dst = (uint4*)&sVA[(kb*64 + t)*32];
        uint4* src4 = (uint4*)buf;
#pragma unroll
        for (int cc = 0; cc < 4; cc++) dst[cc ^ key] = src4[cc];
        if (wid == 0 && ri == 0) {
            float e128 = expf(-64.f*dt);
            float s2, c2v; sincosf(PI_F*dt*n*128.f, &s2, &c2v);
            float pr = 1.f - e128*c2v, pim = -e128*s2;
            float dr = 1.f - wr, di = -wi;
            float dd = 1.f/(dr*dr + di*di);
            sVrs[2*n]   = (pr*dr + pim*di)*dd;
            sVrs[2*n+1] = (pim*dr - pr*di)*dd;
        }
    }
    __syncthreads();

    // phase 1: wave wid handles col-group cg=wid (16 cols); all 4 in parallel
    int rkey = (nl >> 1) & 3;
    {
        int col = wid*16 + nl;
        int b = col >> 2, c = col & 3;
        const unsigned short* up = u + ((size_t)h*16 + b)*512 + c*128;
        f32x4 acc[4];
#pragma unroll
        for (int mt = 0; mt < 4; mt++) acc[mt] = (f32x4){0.f,0.f,0.f,0.f};
#pragma unroll
        for (int kb = 0; kb < 4; kb++) {
            short8 bf = *(const short8*)(up + kb*32 + g*8);
#pragma unroll
            for (int mt = 0; mt < 4; mt++) {
                short8 af = *(const short8*)&sVA[(kb*64 + mt*16 + nl)*32 + ((g ^ rkey) << 3)];
                acc[mt] = __builtin_amdgcn_mfma_f32_16x16x32_bf16(af, bf, acc[mt], 0, 0, 0);
            }
        }
#pragma unroll
        for (int mt = 0; mt < 4; mt++) {
            int j0 = mt*16 + g*4;
            float4 vr = *(const float4*)&sVrs[j0];
            sE[col*68 + j0 + 0] = fmaf(scv, acc[mt][0], shv*vr.x);
            sE[col*68 + j0 + 1] = fmaf(scv, acc[mt][1], shv*vr.y);
            sE[col*68 + j0 + 2] = fmaf(scv, acc[mt][2], shv*vr.z);
            sE[col*68 + j0 + 3] = fmaf(scv, acc[mt][3], shv*vr.w);
        }
    }
    __syncthreads();

    // phase 2+3 partials on wave 0: lane = (n, bh); each handles 8 b's
    if (tid < 64) {
        int n = lane >> 1, bh = lane & 1;
        float e = expf(-0.5f * dt);
        float s_, c_; sincosf(PI_F * dt * n, &s_, &c_);
        float wr = e*c_, wi = e*s_;
        float ar = -0.5f, ai = PI_F * n;
        float den = 1.f / (ar*ar + ai*ai);
        float tr = wr - 1.f, ti = wi;
        float qr = (tr*ar + ti*ai) * den;
        float qi = (ti*ar - tr*ai) * den;
        float c2r = C2[((size_t)h*32 + n)*2], c2i = C2[((size_t)h*32 + n)*2 + 1];
        float crv = c2r*qr - c2i*qi, civ = c2r*qi + c2i*qr;
        float Wr = wr, Wi = wi;
#pragma unroll
        for (int i = 0; i < 7; i++) { float r = Wr*Wr - Wi*Wi; float im = 2.f*Wr*Wi; Wr = r; Wi = im; }
#pragma unroll
        for (int b2 = 0; b2 < 8; b2++) {
            int b = bh*8 + b2;
            float Sr = 0.f, Si = 0.f;
#pragma unroll
            for (int c = 0; c < 4; c++) {
                int col = b*4 + c;
                float er = sE[col*68 + 2*n], ei = sE[col*68 + 2*n + 1];
                float r  = fmaf(Wr, Sr, fmaf(-Wi, Si, er));
                float im = fmaf(Wi, Sr, fmaf( Wr, Si, ei));
                Sr = r; Si = im;
            }
            red[b*33 + n] = crv*Sr - civ*Si;
        }
    }
    __syncthreads();
    if (tid < 16) {
        int b = tid;
        float s = 0.f;
        for (int n2 = 0; n2 < 32; n2++) s += red[b*33 + n2];
        float uv = fmaf(scv, bf2f(u[((size_t)h*16 + b)*512 + 511]), shv);
        x3last[b*1024 + h] = 2.f*s + Dv[h]*uv;
    }
}

// ---------------- decoder head ----------------
__global__ __launch_bounds__(256) void dec_kernel(
    const float* __restrict__ x3last, const float* __restrict__ w1, const float* __restrict__ b1,
    const float* __restrict__ w2, const float* __restrict__ b2, float* __restrict__ out)
{
    __shared__ float xs[1024];
    int b = blockIdx.x, tid = threadIdx.x;
    for (int i = tid; i < 1024; i += 256) xs[i] = x3last[b*1024 + i];
    __syncthreads();
    float z = b1[tid];
    const float* wpt = w1 + (size_t)tid*1024;
    for (int i = 0; i < 1024; i += 4) {
        float4 wv = *(const float4*)(wpt + i);
        z = fmaf(wv.x, xs[i],   z);
        z = fmaf(wv.y, xs[i+1], z);
        z = fmaf(wv.z, xs[i+2], z);
        z = fmaf(wv.w, xs[i+3], z);
    }
    float v = w2[tid] * z;
    for (int o = 32; o > 0; o >>= 1) v += __shfl_down(v, o);
    __shared__ float ps[4];
    if ((tid & 63) == 0) ps[tid >> 6] = v;
    __syncthreads();
    if (tid == 0) out[b] = ps[0] + ps[1] + ps[2] + ps[3] + b2[0];
}

extern "C" void kernel_launch(void* const* d_in, const int* in_sizes, int n_in,
                              void* d_out, int out_size, void* d_ws, size_t ws_size,
                              hipStream_t stream)
{
    const float* x       = (const float*)d_in[0];
    const float* enc_w   = (const float*)d_in[1];
    const float* enc_b   = (const float*)d_in[2];
    const float* s4a_ldt = (const float*)d_in[3];
    const float* s4a_C   = (const float*)d_in[4];
    const float* s4a_D   = (const float*)d_in[5];
    const float* s4b_ldt = (const float*)d_in[6];
    const float* s4b_C   = (const float*)d_in[7];
    const float* s4b_D   = (const float*)d_in[8];
    const float* s4c_ldt = (const float*)d_in[9];
    const float* s4c_C   = (const float*)d_in[10];
    const float* s4c_D   = (const float*)d_in[11];
    const float* b1w[4] = {(const float*)d_in[12], (const float*)d_in[14], (const float*)d_in[16], (const float*)d_in[18]};
    const float* b1b[4] = {(const float*)d_in[13], (const float*)d_in[15], (const float*)d_in[17], (const float*)d_in[19]};
    const float* b2w[4] = {(const float*)d_in[20], (const float*)d_in[22], (const float*)d_in[24], (const float*)d_in[26]};
    const float* b2b[4] = {(const float*)d_in[21], (const float*)d_in[23], (const float*)d_in[25], (const float*)d_in[27]};
    const float* bn1_g  = (const float*)d_in[28];
    const float* bn1_b  = (const float*)d_in[29];
    const float* bn2_g  = (const float*)d_in[30];
    const float* bn2_b  = (const float*)d_in[31];
    const float* dec1_w = (const float*)d_in[32];
    const float* dec1_b = (const float*)d_in[33];
    const float* dec2_w = (const float*)d_in[34];
    const float* dec2_b = (const float*)d_in[35];
    float* out = (float*)d_out;

    char* ws = (char*)d_ws;
    unsigned short* u3    = (unsigned short*)(ws);              // 16.8 MB
    unsigned short* ya    = (unsigned short*)(ws + 16777216);   // 16.8 MB (also yb)
    unsigned short* yb    = ya;
    unsigned short* u2    = (unsigned short*)(ws + 33554432);   // 16.8 MB
    unsigned short* wprep = (unsigned short*)(ws + 88080384);   // 1.67 MB
    unsigned short* TA_a  = (unsigned short*)(ws + 89751552);   // 3.15 MB
    unsigned short* TA_b  = (unsigned short*)(ws + 92897280);   // 12.6 MB
    unsigned short* VA_a  = (unsigned short*)(ws + 105480192);  // 1.05 MB
    unsigned short* VA_b  = (unsigned short*)(ws + 106528768);  // 4.2 MB
    float*          rs_a  = (float*)(ws + 110723072);           // 32 KB
    float*          rs_b  = (float*)(ws + 110755840);           // 128 KB
    float*          Vrs_a = (float*)(ws + 110886912);           // 16 KB
    float*          Vrs_b = (float*)(ws + 110903296);           // 64 KB
    float*          smallp= (float*)(ws + 110968832);
    float* sc1 = smallp;         // 256
    float* sh1 = smallp + 256;   // 256
    float* sc2 = smallp + 512;   // 1024
    float* sh2 = smallp + 1536;  // 1024
    float* x3l = smallp + 2560;  // 16384

    // prep: s4 A-matrices (blocks 0..319) + conv weight repack (blocks 320..3583)
    prep_all<<<3584, 128, 0, stream>>>(
        s4a_ldt, s4a_C, s4a_D, TA_a, VA_a, rs_a, Vrs_a,
        s4b_ldt, s4b_C, s4b_D, TA_b, VA_b, rs_b, Vrs_b,
        b1w[0], b1w[1], b1w[2], b1w[3], b2w[0], b2w[1], b2w[2], b2w[3], wprep);

    // s4a: H=64, NCH=64 (L=8192) -- fused with inline encoder
    s4_layer_fused<64,6,true><<<dim3(16, 64), 256, 0, stream>>>(
        nullptr, x, enc_w, enc_b, VA_a, Vrs_a, TA_a, rs_a, nullptr, nullptr, s4a_ldt, ya);

    // conv block1: ya [64][16][8192] -> u2 [256][16][2048]; TBLK=32 (v8 config)
    conv_mfma4<64,32><<<dim3(64, 16, 1), 256, 0, stream>>>(
        ya, wprep, b1b[0], b1b[1], b1b[2], b1b[3], u2, 8192, 2048);
    bn_stats<<<256, 256, 0, stream>>>(u2, bn1_g, bn1_b, sc1, sh1, 16*2048, 63);

    // s4b: H=256, NCH=16 (L=2048)
    s4_layer_fused<16,4,false><<<dim3(4, 256), 256, 0, stream>>>(
        u2, nullptr, nullptr, nullptr, VA_b, Vrs_b, TA_b, rs_b, sc1, sh1, s4b_ldt, yb);

    // conv block2: yb [256][16][2048] -> u3 [1024][16][512]; TBLK=64 dbuf (v8 config)
    conv_mfma4<256,64><<<dim3(8, 16, 4), 256, 0, stream>>>(
        yb, wprep + 49152, b2b[0], b2b[1], b2b[2], b2b[3], u3, 2048, 512);
    bn_stats<<<1024, 256, 0, stream>>>(u3, bn2_g, bn2_b, sc2, sh2, 16*512, 255);

    // s4c fused v3
    s4c_all<<<1024, 256, 0, stream>>>(u3, sc2, sh2, s4c_ldt, s4c_C, s4c_D, x3l);

    // decoder head
    dec_kernel<<<16, 256, 0, stream>>>(x3l, dec1_w, dec1_b, dec2_w, dec2_b, out);
}

// Round 18
// 294.575 us; speedup vs baseline: 1.1470x; 1.0085x over previous
//
#include <hip/hip_runtime.h>
#include <math.h>

#define PI_F 3.14159265358979323846f

typedef __attribute__((ext_vector_type(8))) short short8;
typedef __attribute__((ext_vector_type(4))) float f32x4;

__device__ __forceinline__ unsigned short f2bf(float f) {
    unsigned int u = __float_as_uint(f);
    unsigned int r = (u + 0x7fffu + ((u >> 16) & 1u)) >> 16;
    return (unsigned short)r;
}
__device__ __forceinline__ float bf2f(unsigned short v) {
    return __uint_as_float((unsigned int)v << 16);
}

// ---------------- prep_all: S4 prep (blocks 0..319) + w repack + bnsum zero ---------
__global__ __launch_bounds__(128) void prep_all(
    const float* __restrict__ ldt_a, const float* __restrict__ C2_a,
    const float* __restrict__ Dv_a,
    unsigned short* __restrict__ TA_a, unsigned short* __restrict__ VA_a,
    float* __restrict__ rs_a, float* __restrict__ Vrs_a,
    const float* __restrict__ ldt_b, const float* __restrict__ C2_b,
    const float* __restrict__ Dv_b,
    unsigned short* __restrict__ TA_b, unsigned short* __restrict__ VA_b,
    float* __restrict__ rs_b, float* __restrict__ Vrs_b,
    const float* __restrict__ w0, const float* __restrict__ w1,
    const float* __restrict__ w2, const float* __restrict__ w3,
    const float* __restrict__ w4, const float* __restrict__ w5,
    const float* __restrict__ w6, const float* __restrict__ w7,
    unsigned short* __restrict__ wprep, float* __restrict__ bnsum)
{
    int bid = blockIdx.x, t = threadIdx.x;
    if (bid >= 320) {
        int z = (bid - 320) * 128 + t;
        if (z < 2560) bnsum[z] = 0.f;           // bsum1[256][2] + bsum2[1024][2]
        const float* wsrc[8] = {w0, w1, w2, w3, w4, w5, w6, w7};
        int e0 = (bid - 320) * 256 + t;
#pragma unroll
        for (int half = 0; half < 2; half++) {
            int e = e0 + half * 128;
            if (e < 835584) {
                int id; int doff; int Cin;
                if (e < 49152) { id = e / 12288; doff = id * 12288; Cin = 64; }
                else { id = 4 + (e - 49152) / 196608; doff = 49152 + (id - 4) * 196608; Cin = 256; }
                int el = e - doff;
                int kb = el / (Cin * 32);
                int rem = el - kb * (Cin * 32);
                int o = rem >> 5, kk = rem & 31;
                int cch = kb / 6, t6 = kb % 6, k = t6 >> 1, chalf = t6 & 1;
                int c = cch * 64 + chalf * 32 + kk;
                wprep[e] = f2bf(wsrc[id][((size_t)o * Cin + c) * 3 + k]);
            }
        }
        return;
    }
    const float* log_dt; const float* C2; const float* Dv;
    unsigned short* TA; unsigned short* VA; float* rs; float* Vrs; int h;
    if (bid < 64) { h = bid;      log_dt = ldt_a; C2 = C2_a; Dv = Dv_a; TA = TA_a; VA = VA_a; rs = rs_a; Vrs = Vrs_a; }
    else          { h = bid - 64; log_dt = ldt_b; C2 = C2_b; Dv = Dv_b; TA = TA_b; VA = VA_b; rs = rs_b; Vrs = Vrs_b; }
    __shared__ float cn[64];
    __shared__ float sK[128];
    __shared__ unsigned short s_w[128 * 66];   // W staged [m][j], pad 66
    float dt = expf(log_dt[h]);
    if (t < 32) {
        int n = t;
        float e = expf(-0.5f*dt);
        float s_, c_; sincosf(PI_F*dt*n, &s_, &c_);
        float wr = e*c_, wi = e*s_;
        float ar = -0.5f, ai = PI_F*n;
        float den = 1.f/(ar*ar + ai*ai);
        float tr = wr - 1.f, ti = wi;
        float qr = (tr*ar + ti*ai)*den;
        float qi = (ti*ar - tr*ai)*den;
        float c2r = C2[((size_t)h*32+n)*2], c2i = C2[((size_t)h*32+n)*2+1];
        cn[2*n]   = 2.f*(c2r*qr - c2i*qi);
        cn[2*n+1] = 2.f*(c2r*qi + c2i*qr);
        float e128 = expf(-64.f*dt);
        float s2, c2v; sincosf(PI_F*dt*n*128.f, &s2, &c2v);
        float pr = 1.f - e128*c2v, pim = -e128*s2;
        float dr = 1.f - wr, di = -wi;
        float dd = 1.f/(dr*dr + di*di);
        Vrs[(size_t)h*64 + 2*n]   = (pr*dr + pim*di)*dd;
        Vrs[(size_t)h*64 + 2*n+1] = (pim*dr - pr*di)*dd;
    }
    __syncthreads();
    {
        float em = expf(-0.5f*dt*t);
        float Kt = 0.f;
        for (int n = 0; n < 32; n++) {
            float s_, c_; sincosf(PI_F*dt*(float)(n*t), &s_, &c_);
            Kt += cn[2*n]*em*c_ - cn[2*n+1]*em*s_;
        }
        sK[t] = Kt + (t == 0 ? Dv[h] : 0.f);
    }
    if (t < 64) {
        int n = t >> 1, ri = t & 1;
        float e = expf(-0.5f*dt);
        float s_, c_; sincosf(PI_F*dt*n, &s_, &c_);
        float wr = e*c_, wi = e*s_;
        float crn = cn[2*n], cin = cn[2*n+1];
        float pr = wr, pim = wi;                    // w^(m+1), m=0
        for (int m = 0; m < 128; m++) {
            float re = crn*pr - cin*pim;
            float im = crn*pim + cin*pr;
            s_w[m*66 + t] = f2bf(ri ? -im : re);
            float nr = pr*wr - pim*wi;
            float ni = pr*wi + pim*wr;
            pr = nr; pim = ni;
        }
    } else {
        int r = t - 64; int n = r >> 1, ri = r & 1;
        float e = expf(-0.5f*dt);
        float s_, c_; sincosf(PI_F*dt*n, &s_, &c_);
        float wr = e*c_, wi = e*s_;
        float cr2 = 1.f, ci2 = 0.f;                 // w^0
        for (int kb = 3; kb >= 0; kb--) {
            unsigned short buf[32];
            for (int kk = 31; kk >= 0; kk--) {
                buf[kk] = f2bf(ri ? ci2 : cr2);
                float nr = cr2*wr - ci2*wi;
                float ni = cr2*wi + ci2*wr;
                cr2 = nr; ci2 = ni;
            }
            uint4* dst = (uint4*)&VA[(((size_t)h*4 + kb)*64 + r)*32];
            uint4* src = (uint4*)buf;
            dst[0]=src[0]; dst[1]=src[1]; dst[2]=src[2]; dst[3]=src[3];
        }
    }
    __syncthreads();
    {
        float acc = 0.f;
        for (int tau = 0; tau <= t; tau++) acc += sK[tau];
        rs[(size_t)h*128 + t] = acc;
    }
    for (int kb = 0; kb < 4; kb++) {
        unsigned short tb[32];
#pragma unroll
        for (int kk = 0; kk < 32; kk++) {
            int col = kb*32 + kk;
            tb[kk] = f2bf((col <= t) ? sK[t - col] : 0.f);
        }
        uint4* dst = (uint4*)&TA[(((size_t)h*6 + kb)*128 + t)*32];
        uint4* src = (uint4*)tb;
        dst[0]=src[0]; dst[1]=src[1]; dst[2]=src[2]; dst[3]=src[3];
    }
    for (int i = t; i < 1024; i += 128) {
        int kb = i >> 9;
        int rem = i & 511;
        int m = rem >> 2, kkg = rem & 3;
        *(uint4*)&TA[(((size_t)h*6 + 4 + kb)*128 + m)*32 + kkg*8] =
            *(const uint4*)&s_w[m*66 + kb*32 + kkg*8];
    }
}

// ---------------- BN partial sums: grid (C, NSLICE); one atomicAdd pair per block ---
__global__ __launch_bounds__(256) void bn_partial(
    const unsigned short* __restrict__ x, float* __restrict__ bnsum,
    int n, int nslice)
{
    int ch = blockIdx.x, sl = blockIdx.y;
    int seg = n / nslice;
    const unsigned short* xp = x + (size_t)ch * n + (size_t)sl * seg;
    float s1 = 0.f, s2 = 0.f;
    for (int i = threadIdx.x*8; i < seg; i += 2048) {
        uint4 raw = *(const uint4*)(xp + i);
        unsigned short us[8]; *(uint4*)us = raw;
#pragma unroll
        for (int j = 0; j < 8; j++) {
            float v = bf2f(us[j]);
            s1 += v; s2 += v*v;
        }
    }
    for (int o = 32; o > 0; o >>= 1) { s1 += __shfl_down(s1, o); s2 += __shfl_down(s2, o); }
    __shared__ float p1[4], p2[4];
    int wv = threadIdx.x >> 6;
    if ((threadIdx.x & 63) == 0) { p1[wv] = s1; p2[wv] = s2; }
    __syncthreads();
    if (threadIdx.x == 0) {
        s1 = p1[0] + p1[1] + p1[2] + p1[3];
        s2 = p2[0] + p2[1] + p2[2] + p2[3];
        atomicAdd(&bnsum[ch*2],     s1);
        atomicAdd(&bnsum[ch*2 + 1], s2);
    }
}

// ---------------- S4 layer fused: [enc] + [BN finalize] + V-GEMM + scan + T/W-GEMM --
template<int NCH, int LOGNCH, bool ENC, bool BN>
__global__ __launch_bounds__(256) void s4_layer_fused(
    const unsigned short* __restrict__ u, const float* __restrict__ xg,
    const float* __restrict__ ew, const float* __restrict__ ebv,
    const unsigned short* __restrict__ VA,
    const float* __restrict__ Vrs, const unsigned short* __restrict__ TA,
    const float* __restrict__ rs,
    const float* __restrict__ bnsum, const float* __restrict__ bng,
    const float* __restrict__ bnb, int bnN, int gmask,
    const float* __restrict__ log_dt,
    unsigned short* __restrict__ yout)
{
    const int L = NCH * 128;
    __shared__ unsigned short s_u[64*200];   // 25600 B
    __shared__ unsigned short s_s[64*72];    // 9216 B
    __shared__ float sE[64*68];              // 17408 B  (total 52224 B)
    int h = blockIdx.y;
    int tid = threadIdx.x;
    int lane = tid & 63, wid = tid >> 6;
    int nl = lane & 15, g = lane >> 4;
    int col0 = blockIdx.x * 64;
    float scv = 1.f, shv = 0.f;
    if constexpr (BN) {
        float s1 = bnsum[h*2], s2 = bnsum[h*2 + 1];
        float m = s1 / (float)bnN;
        float var = s2 / (float)bnN - m*m;
        float rstd = rsqrtf(var + 1e-5f);
        scv = bng[h & gmask] * rstd;
        shv = fmaf(-m, scv, bnb[h & gmask]);
    }

    // stage u (once; serves V-GEMM and T-GEMM)
    if constexpr (ENC) {
        float w0e = ew[2*h], w1e = ew[2*h+1], bbe = ebv[h];
        for (int i = tid; i < 1024; i += 256) {
            int cl = i >> 4, o = i & 15;
            int col = col0 + cl; int b = col >> LOGNCH, c = col & (NCH - 1);
            const float* xp = xg + ((size_t)b*8192 + (size_t)(c*128 + o*8))*2;
            float4 a0 = *(const float4*)xp;
            float4 a1 = *(const float4*)(xp + 4);
            float4 a2 = *(const float4*)(xp + 8);
            float4 a3 = *(const float4*)(xp + 12);
            ushort4 q0, q1;
            q0.x = f2bf(fmaf(w0e, a0.x, fmaf(w1e, a0.y, bbe)));
            q0.y = f2bf(fmaf(w0e, a0.z, fmaf(w1e, a0.w, bbe)));
            q0.z = f2bf(fmaf(w0e, a1.x, fmaf(w1e, a1.y, bbe)));
            q0.w = f2bf(fmaf(w0e, a1.z, fmaf(w1e, a1.w, bbe)));
            q1.x = f2bf(fmaf(w0e, a2.x, fmaf(w1e, a2.y, bbe)));
            q1.y = f2bf(fmaf(w0e, a2.z, fmaf(w1e, a2.w, bbe)));
            q1.z = f2bf(fmaf(w0e, a3.x, fmaf(w1e, a3.y, bbe)));
            q1.w = f2bf(fmaf(w0e, a3.z, fmaf(w1e, a3.w, bbe)));
            *(ushort4*)&s_u[cl*200 + o*8]     = q0;
            *(ushort4*)&s_u[cl*200 + o*8 + 4] = q1;
        }
    } else {
        for (int i = tid; i < 1024; i += 256) {
            int cl = i >> 4, o = i & 15;
            int col = col0 + cl; int b = col >> LOGNCH, c = col & (NCH - 1);
            *(uint4*)&s_u[cl*200 + o*8] =
                *(const uint4*)&u[((size_t)h*16 + b)*L + c*128 + o*8];
        }
    }
    __syncthreads();

    // V-GEMM: wave wid computes E for cols cl = wid*16 + nl (gemm_a math)
    {
        int cl = wid*16 + nl;
        f32x4 acc[4];
#pragma unroll
        for (int mt = 0; mt < 4; mt++) acc[mt] = (f32x4){0.f,0.f,0.f,0.f};
#pragma unroll
        for (int kb = 0; kb < 4; kb++) {
            short8 bf = *(const short8*)&s_u[cl*200 + kb*32 + g*8];
#pragma unroll
            for (int mt = 0; mt < 4; mt++) {
                short8 af = *(const short8*)(VA + (((size_t)h*4 + kb)*64 + mt*16 + nl)*32 + g*8);
                acc[mt] = __builtin_amdgcn_mfma_f32_16x16x32_bf16(af, bf, acc[mt], 0, 0, 0);
            }
        }
#pragma unroll
        for (int mt = 0; mt < 4; mt++) {
            int j0 = mt*16 + g*4;
            float4 vr = *(const float4*)(Vrs + (size_t)h*64 + j0);
            sE[cl*68 + j0 + 0] = fmaf(scv, acc[mt][0], shv*vr.x);
            sE[cl*68 + j0 + 1] = fmaf(scv, acc[mt][1], shv*vr.y);
            sE[cl*68 + j0 + 2] = fmaf(scv, acc[mt][2], shv*vr.z);
            sE[cl*68 + j0 + 3] = fmaf(scv, acc[mt][3], shv*vr.w);
        }
    }
    __syncthreads();

    // chunk scan (mid math)
    constexpr int NB = 64 / NCH;   // 1 (layer a) or 4 (layer b)
    if (tid < NB * 32) {
        int bl = tid >> 5, n = tid & 31;
        float dt = expf(log_dt[h]);
        float e = expf(-0.5f * dt);
        float s_, c_; sincosf(PI_F * dt * n, &s_, &c_);
        float Wr = e*c_, Wi = e*s_;
#pragma unroll
        for (int i = 0; i < 7; i++) { float r = Wr*Wr - Wi*Wi; float im = 2.f*Wr*Wi; Wr = r; Wi = im; }
        float Sr = 0.f, Si = 0.f;
        for (int c2 = 0; c2 < NCH; c2++) {
            float* ep = &sE[(bl*NCH + c2)*68 + 2*n];
            float er = ep[0], ei = ep[1];
            ep[0] = Sr; ep[1] = Si;          // Sini = state BEFORE chunk c2
            float r  = fmaf(Wr, Sr, fmaf(-Wi, Si, er));
            float im = fmaf(Wi, Sr, fmaf( Wr, Si, ei));
            Sr = r; Si = im;
        }
    }
    __syncthreads();

    // convert Sini (fp32 in sE) -> bf16 s_s
    for (int i = tid*4; i < 4096; i += 1024) {
        int cl = i >> 6, j = i & 63;
        ushort4 q;
        q.x = f2bf(sE[cl*68 + j]);
        q.y = f2bf(sE[cl*68 + j+1]);
        q.z = f2bf(sE[cl*68 + j+2]);
        q.w = f2bf(sE[cl*68 + j+3]);
        *(ushort4*)&s_s[cl*72 + j] = q;
    }
    __syncthreads();

    // T-GEMM + W-GEMM + epilogue
    f32x4 accT[2][4], accW[2][4];
#pragma unroll
    for (int a = 0; a < 2; a++)
#pragma unroll
        for (int j = 0; j < 4; j++) { accT[a][j] = (f32x4){0,0,0,0}; accW[a][j] = (f32x4){0,0,0,0}; }
#pragma unroll
    for (int kb = 0; kb < 4; kb++) {
        short8 bfr[4];
#pragma unroll
        for (int j = 0; j < 4; j++)
            bfr[j] = *(const short8*)&s_u[(j*16 + nl)*200 + kb*32 + g*8];
#pragma unroll
        for (int mt2 = 0; mt2 < 2; mt2++) {
            int mtile = wid*2 + mt2;
            short8 af = *(const short8*)&TA[(((size_t)h*6 + kb)*128 + mtile*16 + nl)*32 + g*8];
#pragma unroll
            for (int j = 0; j < 4; j++)
                accT[mt2][j] = __builtin_amdgcn_mfma_f32_16x16x32_bf16(af, bfr[j], accT[mt2][j], 0, 0, 0);
        }
    }
#pragma unroll
    for (int kw = 0; kw < 2; kw++) {
        short8 bfr[4];
#pragma unroll
        for (int j = 0; j < 4; j++)
            bfr[j] = *(const short8*)&s_s[(j*16 + nl)*72 + kw*32 + g*8];
#pragma unroll
        for (int mt2 = 0; mt2 < 2; mt2++) {
            int mtile = wid*2 + mt2;
            short8 af = *(const short8*)&TA[(((size_t)h*6 + 4 + kw)*128 + mtile*16 + nl)*32 + g*8];
#pragma unroll
            for (int j = 0; j < 4; j++)
                accW[mt2][j] = __builtin_amdgcn_mfma_f32_16x16x32_bf16(af, bfr[j], accW[mt2][j], 0, 0, 0);
        }
    }
#pragma unroll
    for (int mt2 = 0; mt2 < 2; mt2++) {
        int m0 = (wid*2 + mt2)*16 + g*4;
        float4 rsv = *(const float4*)&rs[(size_t)h*128 + m0];
#pragma unroll
        for (int j = 0; j < 4; j++) {
            int col = col0 + j*16 + nl; int b = col >> LOGNCH, c = col & (NCH - 1);
            ushort4 q;
            q.x = f2bf(fmaf(scv, accT[mt2][j][0], shv*rsv.x) + accW[mt2][j][0]);
            q.y = f2bf(fmaf(scv, accT[mt2][j][1], shv*rsv.y) + accW[mt2][j][1]);
            q.z = f2bf(fmaf(scv, accT[mt2][j][2], shv*rsv.z) + accW[mt2][j][2]);
            q.w = f2bf(fmaf(scv, accT[mt2][j][3], shv*rsv.w) + accW[mt2][j][3]);
            *(ushort4*)&yout[((size_t)h*16 + b)*L + c*128 + m0] = q;
        }
    }
}

// ---------------- fused 4-dilation conv block via MFMA (v8 config, FROZEN) ----------
// Spill-fragile (rounds 2/5/14/16). ONLY clean config: LDS double-buffer, T14
// load-early/write-late, wave<->dilation remap, conv1 TBLK=32, conv2 TBLK=64,
// bounds (256,2), NO epilogue additions. DO NOT EDIT.
template<int CIN, int TBLK>
__global__ __launch_bounds__(256, 2) void conv_mfma4(
    const unsigned short* __restrict__ u, const unsigned short* __restrict__ wp,
    const float* __restrict__ bs0, const float* __restrict__ bs1,
    const float* __restrict__ bs2, const float* __restrict__ bs3,
    unsigned short* __restrict__ out, int Lin, int Lout)
{
    constexpr int F     = TBLK / 16;
    constexpr int NPOS  = TBLK * 4 + 16;
    constexpr int Q     = NPOS / 4;
    constexpr int NITEM = (NPOS / 8) * 64;
    constexpr int NLD   = (NITEM + 255) / 256;
    constexpr int NCC   = CIN / 64;
    constexpr int NBUF  = (NCC > 1) ? 2 : 1;
    constexpr int BUFSZ = 4 * Q * 64;
    __shared__ unsigned short s_in[NBUF * BUFSZ];

    int tid = threadIdx.x;
    int lane = tid & 63, wid = tid >> 6;      // wid == dilation index d
    int nl = lane & 15, g = lane >> 4;
    int t0 = blockIdx.x * TBLK;
    int b  = blockIdx.y;
    int og = blockIdx.z * 64;
    const int P0 = t0 * 4 - 8;
    const int DIL = 1 << wid;                 // wave-uniform

    f32x4 acc[4][F];
#pragma unroll
    for (int m = 0; m < 4; m++)
#pragma unroll
        for (int f = 0; f < F; f++) acc[m][f] = (f32x4){0.f,0.f,0.f,0.f};

    uint4 stg[NLD];

    auto stage_load = [&](int ccbase) {
#pragma unroll
        for (int j = 0; j < NLD; j++) {
            int i = tid + 256 * j;
            uint4 v; v.x = 0u; v.y = 0u; v.z = 0u; v.w = 0u;
            if (i < NITEM) {
                int ch = i & 63, po = i >> 6;
                int p = P0 + po * 8;
                const unsigned short* gp = u + ((size_t)(ccbase + ch)*16 + b)*Lin;
                if (p >= 0 && p + 8 <= Lin) {
                    v = *(const uint4*)(gp + p);
                } else {
                    alignas(16) unsigned short t8[8];
#pragma unroll
                    for (int j2 = 0; j2 < 8; j2++) {
                        int pj = p + j2;
                        t8[j2] = ((unsigned)pj < (unsigned)Lin) ? gp[pj] : (unsigned short)0;
                    }
                    v = *(const uint4*)t8;
                }
            }
            stg[j] = v;
        }
    };
    auto stage_write = [&](int bufidx) {
        unsigned short* sb = s_in + bufidx * BUFSZ;
#pragma unroll
        for (int j = 0; j < NLD; j++) {
            int i = tid + 256 * j;
            if (i < NITEM) {
                int ch = i & 63, po = i >> 6;
                alignas(16) unsigned short t8[8];
                *(uint4*)t8 = stg[j];
#pragma unroll
                for (int jj = 0; jj < 8; jj++) {
                    int pl = po * 8 + jj;
                    int row = (pl & 3) * Q + (pl >> 2);
                    sb[row * 64 + (ch ^ ((row & 7) << 3))] = t8[jj];
                }
            }
        }
    };

    stage_load(0);
    stage_write(0);
    __syncthreads();

#pragma unroll
    for (int cc = 0; cc < NCC; cc++) {
        if (cc + 1 < NCC) stage_load((cc + 1) * 64);
        const unsigned short* sb = s_in + (NBUF > 1 ? (cc & 1) * BUFSZ : 0);
#pragma unroll
        for (int k = 0; k < 3; ++k) {
            const int off = (k - 1) * DIL + 8;
            const int r = off & 3, s = off >> 2;
#pragma unroll
            for (int chalf = 0; chalf < 2; ++chalf) {
                int kb = cc * 6 + k * 2 + chalf;
                short8 bfr[F];
#pragma unroll
                for (int f = 0; f < F; ++f) {
                    int q = f*16 + nl + s;
                    int row = r * Q + q;
                    bfr[f] = *(const short8*)&sb[row * 64 +
                        ((((chalf << 2) | g) ^ (row & 7)) << 3)];
                }
#pragma unroll
                for (int m = 0; m < 4; ++m) {
                    short8 afrag = *(const short8*)&wp[(size_t)wid*(3*CIN*CIN) +
                        ((size_t)kb*CIN + og + m*16 + nl)*32 + g*8];
#pragma unroll
                    for (int f = 0; f < F; ++f)
                        acc[m][f] = __builtin_amdgcn_mfma_f32_16x16x32_bf16(afrag, bfr[f], acc[m][f], 0, 0, 0);
                }
            }
        }
        if (cc + 1 < NCC) {
            __syncthreads();
            stage_write((cc + 1) & 1);
            __syncthreads();
        }
    }

    const float* bp = (wid == 0) ? bs0 : (wid == 1) ? bs1 : (wid == 2) ? bs2 : bs3;
#pragma unroll
    for (int m = 0; m < 4; ++m) {
#pragma unroll
        for (int f = 0; f < F; ++f) {
            int t = t0 + f*16 + nl;
#pragma unroll
            for (int r2 = 0; r2 < 4; ++r2) {
                int o = og + m*16 + g*4 + r2;
                float v = acc[m][f][r2] + bp[o];
                if (wid) v = v >= 0.f ? v : 0.3f*v;
                out[((size_t)(wid*CIN + o)*16 + b)*Lout + t] = f2bf(v);
            }
        }
    }
}

// ---------------- s4c fused v3 + inline bn2 finalize --------------
__global__ __launch_bounds__(256) void s4c_all(
    const unsigned short* __restrict__ u,
    const float* __restrict__ bnsum, const float* __restrict__ bng,
    const float* __restrict__ bnb,
    const float* __restrict__ log_dt, const float* __restrict__ C2,
    const float* __restrict__ Dv, float* __restrict__ x3last)
{
    __shared__ float sE[64 * 68];              // 17408 B
    __shared__ float red[16 * 33];             // 2112 B
    __shared__ unsigned short sVA[4 * 64 * 32];// 16384 B
    __shared__ alignas(16) float sVrs[64];     // 256 B
    int h = blockIdx.x;
    int tid = threadIdx.x;
    int lane = tid & 63, wid = tid >> 6;
    int nl = lane & 15, g = lane >> 4;
    float dt = expf(log_dt[h]);
    // bn2 finalize: C=1024, n=8192, gmask=255
    float scv, shv;
    {
        float s1 = bnsum[h*2], s2 = bnsum[h*2 + 1];
        float m = s1 / 8192.f;
        float var = s2 / 8192.f - m*m;
        float rstd = rsqrtf(var + 1e-5f);
        scv = bng[h & 255] * rstd;
        shv = fmaf(-m, scv, bnb[h & 255]);
    }

    // build V rows + Vrs: thread (t=lane, kb=wid) builds 32 cols (chunk-swizzled)
    {
        int t = lane, n = t >> 1, ri = t & 1;
        int kb = wid;
        float e = expf(-0.5f*dt);
        float s_, c_; sincosf(PI_F*dt*n, &s_, &c_);
        float wr = e*c_, wi = e*s_;
        int e0 = 96 - kb*32;                     // exponent at (kb, kk=31)
        float em0 = expf(-0.5f*dt*(float)e0);
        float s0, c0; sincosf(PI_F*dt*(float)n*(float)e0, &s0, &c0);
        float cr2 = em0*c0, ci2 = em0*s0;        // w^e0 (e0=0 -> 1,0)
        alignas(16) unsigned short buf[32];
        for (int kk = 31; kk >= 0; kk--) {
            buf[kk] = f2bf(ri ? ci2 : cr2);
            float nr = cr2*wr - ci2*wi;
            float ni = cr2*wi + ci2*wr;
            cr2 = nr; ci2 = ni;
        }
        int key = (t >> 1) & 3;
        uint4* dst = (uint4*)&sVA[(kb*64 + t)*32];
        uint4* src4 = (uint4*)buf;
#pragma unroll
        for (int cc = 0; cc < 4; cc++) dst[cc ^ key] = src4[cc];
        if (wid == 0 && ri == 0) {
            float e128 = expf(-64.f*dt);
            float s2, c2v; sincosf(PI_F*dt*n*128.f, &s2, &c2v);
            float pr = 1.f - e128*c2v, pim = -e128*s2;
            float dr = 1.f - wr, di = -wi;
            float dd = 1.f/(dr*dr + di*di);
            sVrs[2*n]   = (pr*dr + pim*di)*dd;
            sVrs[2*n+1] = (pim*dr - pr*di)*dd;
        }
    }
    __syncthreads();

    // phase 1: wave wid handles col-group cg=wid (16 cols); all 4 in parallel
    int rkey = (nl >> 1) & 3;
    {
        int col = wid*16 + nl;
        int b = col >> 2, c = col & 3;
        const unsigned short* up = u + ((size_t)h*16 + b)*512 + c*128;
        f32x4 acc[4];
#pragma unroll
        for (int mt = 0; mt < 4; mt++) acc[mt] = (f32x4){0.f,0.f,0.f,0.f};
#pragma unroll
        for (int kb = 0; kb < 4; kb++) {
            short8 bf = *(const short8*)(up + kb*32 + g*8);
#pragma unroll
            for (int mt = 0; mt < 4; mt++) {
                short8 af = *(const short8*)&sVA[(kb*64 + mt*16 + nl)*32 + ((g ^ rkey) << 3)];
                acc[mt] = __builtin_amdgcn_mfma_f32_16x16x32_bf16(af, bf, acc[mt], 0, 0, 0);
            }
        }
#pragma unroll
        for (int mt = 0; mt < 4; mt++) {
            int j0 = mt*16 + g*4;
            float4 vr = *(const float4*)&sVrs[j0];
            sE[col*68 + j0 + 0] = fmaf(scv, acc[mt][0], shv*vr.x);
            sE[col*68 + j0 + 1] = fmaf(scv, acc[mt][1], shv*vr.y);
            sE[col*68 + j0 + 2] = fmaf(scv, acc[mt][2], shv*vr.z);
            sE[col*68 + j0 + 3] = fmaf(scv, acc[mt][3], shv*vr.w);
        }
    }
    __syncthreads();

    // phase 2+3 partials on wave 0: lane = (n, bh); each handles 8 b's
    if (tid < 64) {
        int n = lane >> 1, bh = lane & 1;
        float e = expf(-0.5f * dt);
        float s_, c_; sincosf(PI_F * dt * n, &s_, &c_);
        float wr = e*c_, wi = e*s_;
        float ar = -0.5f, ai = PI_F * n;
        float den = 1.f / (ar*ar + ai*ai);
        float tr = wr - 1.f, ti = wi;
        float qr = (tr*ar + ti*ai) * den;
        float qi = (ti*ar - tr*ai) * den;
        float c2r = C2[((size_t)h*32 + n)*2], c2i = C2[((size_t)h*32 + n)*2 + 1];
        float crv = c2r*qr - c2i*qi, civ = c2r*qi + c2i*qr;
        float Wr = wr, Wi = wi;
#pragma unroll
        for (int i = 0; i < 7; i++) { float r = Wr*Wr - Wi*Wi; float im = 2.f*Wr*Wi; Wr = r; Wi = im; }
#pragma unroll
        for (int b2 = 0; b2 < 8; b2++) {
            int b = bh*8 + b2;
            float Sr = 0.f, Si = 0.f;
#pragma unroll
            for (int c = 0; c < 4; c++) {
                int col = b*4 + c;
                float er = sE[col*68 + 2*n], ei = sE[col*68 + 2*n + 1];
                float r  = fmaf(Wr, Sr, fmaf(-Wi, Si, er));
                float im = fmaf(Wi, Sr, fmaf( Wr, Si, ei));
                Sr = r; Si = im;
            }
            red[b*33 + n] = crv*Sr - civ*Si;
        }
    }
    __syncthreads();
    if (tid < 16) {
        int b = tid;
        float s = 0.f;
        for (int n2 = 0; n2 < 32; n2++) s += red[b*33 + n2];
        float uv = fmaf(scv, bf2f(u[((size_t)h*16 + b)*512 + 511]), shv);
        x3last[b*1024 + h] = 2.f*s + Dv[h]*uv;
    }
}

// ---------------- decoder head ----------------
__global__ __launch_bounds__(256) void dec_kernel(
    const float* __restrict__ x3last, const float* __restrict__ w1, const float* __restrict__ b1,
    const float* __restrict__ w2, const float* __restrict__ b2, float* __restrict__ out)
{
    __shared__ float xs[1024];
    int b = blockIdx.x, tid = threadIdx.x;
    for (int i = tid; i < 1024; i += 256) xs[i] = x3last[b*1024 + i];
    __syncthreads();
    float z = b1[tid];
    const float* wpt = w1 + (size_t)tid*1024;
    for (int i = 0; i < 1024; i += 4) {
        float4 wv = *(const float4*)(wpt + i);
        z = fmaf(wv.x, xs[i],   z);
        z = fmaf(wv.y, xs[i+1], z);
        z = fmaf(wv.z, xs[i+2], z);
        z = fmaf(wv.w, xs[i+3], z);
    }
    float v = w2[tid] * z;
    for (int o = 32; o > 0; o >>= 1) v += __shfl_down(v, o);
    __shared__ float ps[4];
    if ((tid & 63) == 0) ps[tid >> 6] = v;
    __syncthreads();
    if (tid == 0) out[b] = ps[0] + ps[1] + ps[2] + ps[3] + b2[0];
}

extern "C" void kernel_launch(void* const* d_in, const int* in_sizes, int n_in,
                              void* d_out, int out_size, void* d_ws, size_t ws_size,
                              hipStream_t stream)
{
    const float* x       = (const float*)d_in[0];
    const float* enc_w   = (const float*)d_in[1];
    const float* enc_b   = (const float*)d_in[2];
    const float* s4a_ldt = (const float*)d_in[3];
    const float* s4a_C   = (const float*)d_in[4];
    const float* s4a_D   = (const float*)d_in[5];
    const float* s4b_ldt = (const float*)d_in[6];
    const float* s4b_C   = (const float*)d_in[7];
    const float* s4b_D   = (const float*)d_in[8];
    const float* s4c_ldt = (const float*)d_in[9];
    const float* s4c_C   = (const float*)d_in[10];
    const float* s4c_D   = (const float*)d_in[11];
    const float* b1w[4] = {(const float*)d_in[12], (const float*)d_in[14], (const float*)d_in[16], (const float*)d_in[18]};
    const float* b1b[4] = {(const float*)d_in[13], (const float*)d_in[15], (const float*)d_in[17], (const float*)d_in[19]};
    const float* b2w[4] = {(const float*)d_in[20], (const float*)d_in[22], (const float*)d_in[24], (const float*)d_in[26]};
    const float* b2b[4] = {(const float*)d_in[21], (const float*)d_in[23], (const float*)d_in[25], (const float*)d_in[27]};
    const float* bn1_g  = (const float*)d_in[28];
    const float* bn1_b  = (const float*)d_in[29];
    const float* bn2_g  = (const float*)d_in[30];
    const float* bn2_b  = (const float*)d_in[31];
    const float* dec1_w = (const float*)d_in[32];
    const float* dec1_b = (const float*)d_in[33];
    const float* dec2_w = (const float*)d_in[34];
    const float* dec2_b = (const float*)d_in[35];
    float* out = (float*)d_out;

    char* ws = (char*)d_ws;
    unsigned short* u3    = (unsigned short*)(ws);              // 16.8 MB
    unsigned short* ya    = (unsigned short*)(ws + 16777216);   // 16.8 MB (also yb)
    unsigned short* yb    = ya;
    unsigned short* u2    = (unsigned short*)(ws + 33554432);   // 16.8 MB
    unsigned short* wprep = (unsigned short*)(ws + 88080384);   // 1.67 MB
    unsigned short* TA_a  = (unsigned short*)(ws + 89751552);   // 3.15 MB
    unsigned short* TA_b  = (unsigned short*)(ws + 92897280);   // 12.6 MB
    unsigned short* VA_a  = (unsigned short*)(ws + 105480192);  // 1.05 MB
    unsigned short* VA_b  = (unsigned short*)(ws + 106528768);  // 4.2 MB
    float*          rs_a  = (float*)(ws + 110723072);           // 32 KB
    float*          rs_b  = (float*)(ws + 110755840);           // 128 KB
    float*          Vrs_a = (float*)(ws + 110886912);           // 16 KB
    float*          Vrs_b = (float*)(ws + 110903296);           // 64 KB
    float*          smallp= (float*)(ws + 110968832);
    float* bsum1 = smallp;           // [256][2]  = 512 floats
    float* bsum2 = smallp + 512;     // [1024][2] = 2048 floats
    float* x3l   = smallp + 2560;    // 16384 floats

    // prep: s4 A-matrices + conv weight repack + bnsum zero (one launch)
    prep_all<<<3584, 128, 0, stream>>>(
        s4a_ldt, s4a_C, s4a_D, TA_a, VA_a, rs_a, Vrs_a,
        s4b_ldt, s4b_C, s4b_D, TA_b, VA_b, rs_b, Vrs_b,
        b1w[0], b1w[1], b1w[2], b1w[3], b2w[0], b2w[1], b2w[2], b2w[3],
        wprep, bsum1);

    // s4a: fused with inline encoder
    s4_layer_fused<64,6,true,false><<<dim3(16, 64), 256, 0, stream>>>(
        nullptr, x, enc_w, enc_b, VA_a, Vrs_a, TA_a, rs_a,
        nullptr, nullptr, nullptr, 0, 0, s4a_ldt, ya);

    // conv block1: ya -> u2 (frozen v8 config)
    conv_mfma4<64,32><<<dim3(64, 16, 1), 256, 0, stream>>>(
        ya, wprep, b1b[0], b1b[1], b1b[2], b1b[3], u2, 8192, 2048);
    // bn1 partials: 256 ch x 8 slices = 2048 blocks
    bn_partial<<<dim3(256, 8), 256, 0, stream>>>(u2, bsum1, 16*2048, 8);

    // s4b: inline bn1 finalize (n=32768, gmask=63)
    s4_layer_fused<16,4,false,true><<<dim3(4, 256), 256, 0, stream>>>(
        u2, nullptr, nullptr, nullptr, VA_b, Vrs_b, TA_b, rs_b,
        bsum1, bn1_g, bn1_b, 32768, 63, s4b_ldt, yb);

    // conv block2: yb -> u3 (frozen v8 config)
    conv_mfma4<256,64><<<dim3(8, 16, 4), 256, 0, stream>>>(
        yb, wprep + 49152, b2b[0], b2b[1], b2b[2], b2b[3], u3, 2048, 512);
    // bn2 partials: 1024 ch x 2 slices = 2048 blocks
    bn_partial<<<dim3(1024, 2), 256, 0, stream>>>(u3, bsum2, 16*512, 2);

    // s4c fused (inline bn2 finalize)
    s4c_all<<<1024, 256, 0, stream>>>(u3, bsum2, bn2_g, bn2_b, s4c_ldt, s4c_C, s4c_D, x3l);

    // decoder head
    dec_kernel<<<16, 256, 0, stream>>>(x3l, dec1_w, dec1_b, dec2_w, dec2_b, out);
}